// Round 1
// baseline (483.364 us; speedup 1.0000x reference)
//
#include <hip/hip_runtime.h>

// MAB block: q=QWq^T+bq, k=VWk^T+bk, v=VWv^T+bv, 8-head masked attention
// with residual (Oh = qh + A@vh), merge heads, out = O + relu(O Wo^T + bo).
// B=4, N=2048, DIM=512, HEADS=8, d=64. All compute bf16-MFMA with f32 accum.

typedef __attribute__((ext_vector_type(8))) __bf16 bf16x8;
typedef __attribute__((ext_vector_type(4))) float f32x4;

#define DEV static __device__ __forceinline__

constexpr int DIMC = 512;
constexpr int NTOK = 2048;
constexpr int BB   = 4;
constexpr int MTOK = BB * NTOK;          // 8192
constexpr float SCALE = 0.04419417382415922f;  // 1/sqrt(512)

DEV unsigned short f2b(float f) {        // f32 -> bf16 bits, RNE (finite inputs)
  unsigned u = __float_as_uint(f);
  u = (u + 0x7FFFu + ((u >> 16) & 1u)) >> 16;
  return (unsigned short)u;
}
DEV float b2f(unsigned short b) { return __uint_as_float(((unsigned)b) << 16); }

// ---------------- f32 -> bf16 conversion (vectorized) ----------------
__global__ void cvt_kernel(const float* __restrict__ in,
                           unsigned short* __restrict__ out, int n4) {
  int i = blockIdx.x * blockDim.x + threadIdx.x;
  if (i >= n4) return;
  float4 v = reinterpret_cast<const float4*>(in)[i];
  ushort4 o;
  o.x = f2b(v.x); o.y = f2b(v.y); o.z = f2b(v.z); o.w = f2b(v.w);
  reinterpret_cast<ushort4*>(out)[i] = o;
}

// ---------------- mask dtype detection ----------------
// If mask is 1-byte bool: bytes at i%4==1 are ~90% nonzero.
// If mask is int32/float32 (0/1 values): bytes at i%4==1 are always 0.
__global__ void detect_kernel(const unsigned char* __restrict__ m,
                              int* __restrict__ flag) {
  int any = 0;
  for (int i = threadIdx.x; i < BB * NTOK; i += blockDim.x)
    if ((i & 3) == 1 && m[i]) any = 1;
  if (any) atomicOr(flag, 1);
}

// ---------------- NT GEMM: out[m,n] = sum_k A[m,k]*W[n,k] + bias[n] ----------------
// A [M,512] bf16 row-major, W [512,512] bf16 row-major ([n][k]).
// 4 waves (2x2), each wave a 64x64 tile; block tile 128x128. Direct-global frags.
// MODE 0: outb[m*512+n] = bf16(val)
// MODE 1: (v-proj) write transposed per head: vt[(b*8+h)*64+d][t]
// MODE 2: outf[m*512+n] = resid[m*512+n] + relu(val)
template <int MODE>
__global__ __launch_bounds__(256) void gemm_nt(
    const unsigned short* __restrict__ A, const unsigned short* __restrict__ W,
    const float* __restrict__ bias, unsigned short* __restrict__ outb,
    const float* __restrict__ resid, float* __restrict__ outf) {
  const int lane = threadIdx.x & 63;
  const int w = threadIdx.x >> 6;
  const int r = lane & 15, g = lane >> 4;
  const int row0 = blockIdx.x * 128 + (w >> 1) * 64;
  const int col0 = blockIdx.y * 128 + (w & 1) * 64;

  f32x4 acc[4][4];
#pragma unroll
  for (int i = 0; i < 4; ++i)
#pragma unroll
    for (int j = 0; j < 4; ++j) acc[i][j] = f32x4{0.f, 0.f, 0.f, 0.f};

#pragma unroll 2
  for (int kk = 0; kk < DIMC; kk += 32) {
    bf16x8 af[4], bw[4];
#pragma unroll
    for (int i = 0; i < 4; ++i)
      af[i] = *reinterpret_cast<const bf16x8*>(
          A + (size_t)(row0 + i * 16 + r) * DIMC + kk + g * 8);
#pragma unroll
    for (int j = 0; j < 4; ++j)
      bw[j] = *reinterpret_cast<const bf16x8*>(
          W + (size_t)(col0 + j * 16 + r) * DIMC + kk + g * 8);
#pragma unroll
    for (int i = 0; i < 4; ++i)
#pragma unroll
      for (int j = 0; j < 4; ++j)
        acc[i][j] = __builtin_amdgcn_mfma_f32_16x16x32_bf16(af[i], bw[j],
                                                            acc[i][j], 0, 0, 0);
  }

#pragma unroll
  for (int i = 0; i < 4; ++i) {
#pragma unroll
    for (int j = 0; j < 4; ++j) {
#pragma unroll
      for (int q = 0; q < 4; ++q) {
        int m = row0 + i * 16 + g * 4 + q;
        int n = col0 + j * 16 + r;
        float val = acc[i][j][q] + bias[n];
        if (MODE == 0) {
          outb[(size_t)m * DIMC + n] = f2b(val);
        } else if (MODE == 1) {
          int bidx = m >> 11, t = m & 2047, h = n >> 6, d = n & 63;
          outb[(size_t)((bidx * 8 + h) * 64 + d) * NTOK + t] = f2b(val);
        } else {
          float o = resid[(size_t)m * DIMC + n];
          outf[(size_t)m * DIMC + n] = o + fmaxf(val, 0.f);
        }
      }
    }
  }
}

// ---------------- fused masked attention with residual ----------------
// grid: (N/64, B*H). 4 waves/block, wave handles 16 q-rows, 64-key tiles,
// online softmax. qb/kb [8192,512] bf16; vt [512 (bh*64+d)][2048] bf16.
// Writes Of32 (f32) and Ob (bf16), layout [8192,512] head-merged.
__global__ __launch_bounds__(256) void attn_kernel(
    const unsigned short* __restrict__ qb, const unsigned short* __restrict__ kb,
    const unsigned short* __restrict__ vt, const unsigned char* __restrict__ mask8,
    const int* __restrict__ flagp, float* __restrict__ Of32,
    unsigned short* __restrict__ Ob) {
  __shared__ unsigned short P[4][16][80];  // padded stride 80 (160B, 16B-aligned)
  const int lane = threadIdx.x & 63;
  const int w = threadIdx.x >> 6;
  const int r = lane & 15, g = lane >> 4;
  const int bh = blockIdx.y, b = bh >> 3, h = bh & 7;
  const int q0 = blockIdx.x * 64 + w * 16;
  const size_t rowbase = (size_t)b * NTOK;
  const int flag = *flagp;
  const unsigned int* mask32 = reinterpret_cast<const unsigned int*>(mask8);

  // Q fragments (A-operand): row=lane&15, k-chunk=(lane>>4)*8, 2 steps of d
  bf16x8 aq[2];
#pragma unroll
  for (int ks = 0; ks < 2; ++ks)
    aq[ks] = *reinterpret_cast<const bf16x8*>(
        qb + (rowbase + q0 + r) * DIMC + h * 64 + ks * 32 + g * 8);

  float mrun[4] = {-1e30f, -1e30f, -1e30f, -1e30f};
  float lrun[4] = {0.f, 0.f, 0.f, 0.f};
  f32x4 oacc[4];
#pragma unroll
  for (int f = 0; f < 4; ++f) oacc[f] = f32x4{0.f, 0.f, 0.f, 0.f};

  for (int kt = 0; kt < NTOK; kt += 64) {
    // ---- QK^T: 16 q-rows x 64 keys ----
    f32x4 s[4];
#pragma unroll
    for (int f = 0; f < 4; ++f) s[f] = f32x4{0.f, 0.f, 0.f, 0.f};
#pragma unroll
    for (int ks = 0; ks < 2; ++ks)
#pragma unroll
      for (int f = 0; f < 4; ++f) {
        bf16x8 kf = *reinterpret_cast<const bf16x8*>(
            kb + (rowbase + kt + f * 16 + r) * DIMC + h * 64 + ks * 32 + g * 8);
        s[f] = __builtin_amdgcn_mfma_f32_16x16x32_bf16(aq[ks], kf, s[f], 0, 0, 0);
      }
    // ---- scale + mask (exactly -100.0 like the reference) ----
#pragma unroll
    for (int f = 0; f < 4; ++f) {
      int mi = b * NTOK + kt + f * 16 + r;
      bool valid = flag ? (mask8[mi] != 0) : (mask32[mi] != 0);
#pragma unroll
      for (int q = 0; q < 4; ++q)
        s[f][q] = valid ? s[f][q] * SCALE : -100.0f;
    }
    // ---- online softmax, rows fully wave-parallel ----
    float corr[4];
#pragma unroll
    for (int j = 0; j < 4; ++j) {
      float tm = fmaxf(fmaxf(s[0][j], s[1][j]), fmaxf(s[2][j], s[3][j]));
      tm = fmaxf(tm, __shfl_xor(tm, 1));
      tm = fmaxf(tm, __shfl_xor(tm, 2));
      tm = fmaxf(tm, __shfl_xor(tm, 4));
      tm = fmaxf(tm, __shfl_xor(tm, 8));
      float mnew = fmaxf(mrun[j], tm);
      corr[j] = __expf(mrun[j] - mnew);
      float rs = 0.f;
#pragma unroll
      for (int f = 0; f < 4; ++f) {
        float p = __expf(s[f][j] - mnew);
        s[f][j] = p;
        rs += p;
      }
      rs += __shfl_xor(rs, 1);
      rs += __shfl_xor(rs, 2);
      rs += __shfl_xor(rs, 4);
      rs += __shfl_xor(rs, 8);
      lrun[j] = lrun[j] * corr[j] + rs;
      mrun[j] = mnew;
#pragma unroll
      for (int f = 0; f < 4; ++f) oacc[f][j] *= corr[j];
    }
    // ---- transpose P through LDS (D-layout -> A-layout) ----
#pragma unroll
    for (int f = 0; f < 4; ++f)
#pragma unroll
      for (int j = 0; j < 4; ++j)
        P[w][g * 4 + j][f * 16 + r] = f2b(s[f][j]);
    __syncthreads();
    // ---- PV: oacc += P @ V ----
#pragma unroll
    for (int ks = 0; ks < 2; ++ks) {
      bf16x8 pa = *reinterpret_cast<const bf16x8*>(&P[w][r][ks * 32 + g * 8]);
#pragma unroll
      for (int f = 0; f < 4; ++f) {
        bf16x8 vf = *reinterpret_cast<const bf16x8*>(
            vt + ((size_t)bh * 64 + f * 16 + r) * NTOK + kt + ks * 32 + g * 8);
        oacc[f] = __builtin_amdgcn_mfma_f32_16x16x32_bf16(pa, vf, oacc[f], 0, 0, 0);
      }
    }
    __syncthreads();
  }
  // ---- epilogue: O = q + PV/l ; write f32 and bf16 ----
#pragma unroll
  for (int j = 0; j < 4; ++j) {
    float inv = 1.0f / lrun[j];
    int qrow = q0 + g * 4 + j;
#pragma unroll
    for (int f = 0; f < 4; ++f) {
      int col = h * 64 + f * 16 + r;
      size_t idx = (rowbase + qrow) * DIMC + col;
      float o = b2f(qb[idx]) + oacc[f][j] * inv;
      Of32[idx] = o;
      Ob[idx] = f2b(o);
    }
  }
}

extern "C" void kernel_launch(void* const* d_in, const int* in_sizes, int n_in,
                              void* d_out, int out_size, void* d_ws, size_t ws_size,
                              hipStream_t stream) {
  const float* Q  = (const float*)d_in[0];
  const float* V  = (const float*)d_in[1];
  const unsigned char* mask = (const unsigned char*)d_in[2];
  const float* Wq = (const float*)d_in[3];
  const float* bq = (const float*)d_in[4];
  const float* Wk = (const float*)d_in[5];
  const float* bk = (const float*)d_in[6];
  const float* Wv = (const float*)d_in[7];
  const float* bv = (const float*)d_in[8];
  const float* Wo = (const float*)d_in[9];
  const float* bo = (const float*)d_in[10];

  char* ws = (char*)d_ws;
  size_t off = 0;
  auto alloc = [&](size_t bytes) -> void* {
    void* p = ws + off;
    off += (bytes + 255) & ~(size_t)255;
    return p;
  };
  int* flag = (int*)alloc(4);
  unsigned short* Qb  = (unsigned short*)alloc((size_t)MTOK * DIMC * 2);
  unsigned short* Vb  = (unsigned short*)alloc((size_t)MTOK * DIMC * 2);
  unsigned short* Wqb = (unsigned short*)alloc((size_t)DIMC * DIMC * 2);
  unsigned short* Wkb = (unsigned short*)alloc((size_t)DIMC * DIMC * 2);
  unsigned short* Wvb = (unsigned short*)alloc((size_t)DIMC * DIMC * 2);
  unsigned short* Wob = (unsigned short*)alloc((size_t)DIMC * DIMC * 2);
  unsigned short* qbf = (unsigned short*)alloc((size_t)MTOK * DIMC * 2);
  unsigned short* kbf = (unsigned short*)alloc((size_t)MTOK * DIMC * 2);
  unsigned short* vtb = (unsigned short*)alloc((size_t)MTOK * DIMC * 2);
  unsigned short* Obf = (unsigned short*)alloc((size_t)MTOK * DIMC * 2);
  // Of32 (16MB) aliases Qb+Vb (consumed before attention runs)
  float* Of32 = (float*)Qb;

  hipMemsetAsync(flag, 0, 4, stream);
  detect_kernel<<<1, 256, 0, stream>>>(mask, flag);

  const int n4t = MTOK * DIMC / 4;
  cvt_kernel<<<(n4t + 255) / 256, 256, 0, stream>>>(Q, Qb, n4t);
  cvt_kernel<<<(n4t + 255) / 256, 256, 0, stream>>>(V, Vb, n4t);
  const int n4w = DIMC * DIMC / 4;
  cvt_kernel<<<(n4w + 255) / 256, 256, 0, stream>>>(Wq, Wqb, n4w);
  cvt_kernel<<<(n4w + 255) / 256, 256, 0, stream>>>(Wk, Wkb, n4w);
  cvt_kernel<<<(n4w + 255) / 256, 256, 0, stream>>>(Wv, Wvb, n4w);
  cvt_kernel<<<(n4w + 255) / 256, 256, 0, stream>>>(Wo, Wob, n4w);

  dim3 gg(MTOK / 128, DIMC / 128);  // 64 x 4
  gemm_nt<0><<<gg, 256, 0, stream>>>(Qb, Wqb, bq, qbf, nullptr, nullptr);
  gemm_nt<0><<<gg, 256, 0, stream>>>(Vb, Wkb, bk, kbf, nullptr, nullptr);
  gemm_nt<1><<<gg, 256, 0, stream>>>(Vb, Wvb, bv, vtb, nullptr, nullptr);

  attn_kernel<<<dim3(NTOK / 64, BB * 8), 256, 0, stream>>>(
      qbf, kbf, vtb, mask, flag, Of32, Obf);

  gemm_nt<2><<<gg, 256, 0, stream>>>(Obf, Wob, bo, nullptr, Of32, (float*)d_out);
}

// Round 2
// 218.216 us; speedup vs baseline: 2.2151x; 2.2151x over previous
//
#include <hip/hip_runtime.h>

// MAB block: q=QWq^T+bq, k=VWk^T+bk, v=VWv^T+bv, 8-head masked attention
// with residual (Oh = qh + A@vh), merge heads, out = O + relu(O Wo^T + bo).
// B=4, N=2048, DIM=512, HEADS=8, d=64. All compute bf16-MFMA with f32 accum.

typedef __attribute__((ext_vector_type(8))) __bf16 bf16x8;
typedef __attribute__((ext_vector_type(4))) float f32x4;

#define DEV static __device__ __forceinline__

constexpr int DIMC = 512;
constexpr int NTOK = 2048;
constexpr int BB   = 4;
constexpr int MTOK = BB * NTOK;          // 8192
constexpr float SCALE = 0.04419417382415922f;            // 1/sqrt(512)
constexpr float SCALE2 = SCALE * 1.4426950408889634f;    // *log2(e)
constexpr float MASKV2 = -100.0f * 1.4426950408889634f;  // -100 in exp2 domain

DEV unsigned short f2b(float f) {        // f32 -> bf16 bits, RNE (finite inputs)
  unsigned u = __float_as_uint(f);
  u = (u + 0x7FFFu + ((u >> 16) & 1u)) >> 16;
  return (unsigned short)u;
}
DEV float b2f(unsigned short b) { return __uint_as_float(((unsigned)b) << 16); }

DEV unsigned cvtpk(float a, float b) {   // {lo=bf16(a), hi=bf16(b)}
  unsigned r;
  asm("v_cvt_pk_bf16_f32 %0, %1, %2" : "=v"(r) : "v"(a), "v"(b));
  return r;
}

DEV void async_cp16(const unsigned short* src, unsigned short* dst) {
  __builtin_amdgcn_global_load_lds(
      (const __attribute__((address_space(1))) void*)(src),
      (__attribute__((address_space(3))) void*)(dst), 16, 0, 0);
}

// ---------------- f32 -> bf16 conversion (vectorized) ----------------
__global__ void cvt_kernel(const float* __restrict__ in,
                           unsigned short* __restrict__ out, int n4) {
  int i = blockIdx.x * blockDim.x + threadIdx.x;
  if (i >= n4) return;
  float4 v = reinterpret_cast<const float4*>(in)[i];
  ushort4 o;
  o.x = f2b(v.x); o.y = f2b(v.y); o.z = f2b(v.z); o.w = f2b(v.w);
  reinterpret_cast<ushort4*>(out)[i] = o;
}

// ---------------- mask dtype detection ----------------
// If mask is 1-byte bool: bytes at i%4==1 are ~90% nonzero.
// If mask is int32/float32 (0/1 values): bytes at i%4==1 are always 0.
__global__ void detect_kernel(const unsigned char* __restrict__ m,
                              int* __restrict__ flag) {
  int any = 0;
  for (int i = threadIdx.x; i < BB * NTOK; i += blockDim.x)
    if ((i & 3) == 1 && m[i]) any = 1;
  if (any) atomicOr(flag, 1);
}

// ---------------- NT GEMM: out[m,n] = sum_k A[m,k]*W[n,k] + bias[n] ----------------
// A [M,512] bf16 row-major, W [512,512] bf16 row-major ([n][k]).
// 4 waves (2x2), each wave a 64x64 tile; block tile 128x128. Direct-global frags.
// MODE 0: outb[m*512+n] = bf16(val)
// MODE 1: (v-proj) write transposed per head: vt[(b*8+h)*64+d][t]
// MODE 2: outf[m*512+n] = resid[m*512+n] + relu(val)
template <int MODE>
__global__ __launch_bounds__(256) void gemm_nt(
    const unsigned short* __restrict__ A, const unsigned short* __restrict__ W,
    const float* __restrict__ bias, unsigned short* __restrict__ outb,
    const float* __restrict__ resid, float* __restrict__ outf) {
  const int lane = threadIdx.x & 63;
  const int w = threadIdx.x >> 6;
  const int r = lane & 15, g = lane >> 4;
  const int row0 = blockIdx.x * 128 + (w >> 1) * 64;
  const int col0 = blockIdx.y * 128 + (w & 1) * 64;

  f32x4 acc[4][4];
#pragma unroll
  for (int i = 0; i < 4; ++i)
#pragma unroll
    for (int j = 0; j < 4; ++j) acc[i][j] = f32x4{0.f, 0.f, 0.f, 0.f};

#pragma unroll 2
  for (int kk = 0; kk < DIMC; kk += 32) {
    bf16x8 af[4], bw[4];
#pragma unroll
    for (int i = 0; i < 4; ++i)
      af[i] = *reinterpret_cast<const bf16x8*>(
          A + (size_t)(row0 + i * 16 + r) * DIMC + kk + g * 8);
#pragma unroll
    for (int j = 0; j < 4; ++j)
      bw[j] = *reinterpret_cast<const bf16x8*>(
          W + (size_t)(col0 + j * 16 + r) * DIMC + kk + g * 8);
#pragma unroll
    for (int i = 0; i < 4; ++i)
#pragma unroll
      for (int j = 0; j < 4; ++j)
        acc[i][j] = __builtin_amdgcn_mfma_f32_16x16x32_bf16(af[i], bw[j],
                                                            acc[i][j], 0, 0, 0);
  }

#pragma unroll
  for (int i = 0; i < 4; ++i) {
#pragma unroll
    for (int j = 0; j < 4; ++j) {
#pragma unroll
      for (int q = 0; q < 4; ++q) {
        int m = row0 + i * 16 + g * 4 + q;
        int n = col0 + j * 16 + r;
        float val = acc[i][j][q] + bias[n];
        if (MODE == 0) {
          outb[(size_t)m * DIMC + n] = f2b(val);
        } else if (MODE == 1) {
          int bidx = m >> 11, t = m & 2047, h = n >> 6, d = n & 63;
          outb[(size_t)((bidx * 8 + h) * 64 + d) * NTOK + t] = f2b(val);
        } else {
          float o = resid[(size_t)m * DIMC + n];
          outf[(size_t)m * DIMC + n] = o + fmaxf(val, 0.f);
        }
      }
    }
  }
}

// ---------------- fused masked attention with residual ----------------
// grid: (N/128, B*H). 4 waves/block, wave owns 32 q-rows (2x16 sub-tiles).
// K/V 64-key tiles double-buffered in LDS (global_load_lds, XOR-swizzled via
// pre-swizzled source). Swapped QK^T (mfma(K,Q)) so each lane owns one q-row's
// keys -> softmax is in-lane + 2 shfl_xor. P packed bf16 -> swizzled per-wave
// LDS tile -> PV A-fragment. Online softmax in exp2 domain.
__global__ __launch_bounds__(256) void attn_kernel(
    const unsigned short* __restrict__ qb, const unsigned short* __restrict__ kb,
    const unsigned short* __restrict__ vt, const unsigned char* __restrict__ mask8,
    const int* __restrict__ flagp, float* __restrict__ Of32,
    unsigned short* __restrict__ Ob) {
  __shared__ unsigned short Kt[2][64 * 64];   // 8KB each, swizzled rows of 128B
  __shared__ unsigned short Vt[2][64 * 64];
  __shared__ unsigned short Pt[4][32 * 64];   // per-wave P tile, swizzled
  __shared__ unsigned char Msk[NTOK];

  const int tid = threadIdx.x;
  const int lane = tid & 63;
  const int w = tid >> 6;
  const int r = lane & 15, g = lane >> 4;
  const int bh = blockIdx.y, b = bh >> 3, h = bh & 7;
  const int q0w = blockIdx.x * 128 + w * 32;
  const size_t rowbase = (size_t)b * NTOK;
  const int flag = *flagp;
  const unsigned* mask32 = (const unsigned*)mask8;

  // normalize mask into LDS (1 byte per key)
  for (int i = tid; i < NTOK; i += 256) {
    unsigned v = flag ? (unsigned)mask8[b * NTOK + i] : mask32[b * NTOK + i];
    Msk[i] = v ? 1 : 0;
  }

  // Q fragments (B-operand): n=q-row at lane r, k-chunk g*8
  bf16x8 aq[2][2];
#pragma unroll
  for (int qi = 0; qi < 2; ++qi)
#pragma unroll
    for (int ks = 0; ks < 2; ++ks)
      aq[qi][ks] = *reinterpret_cast<const bf16x8*>(
          qb + (rowbase + q0w + qi * 16 + r) * DIMC + h * 64 + ks * 32 + g * 8);

  // stage a 64x64 bf16 tile (rows of 128B) with XOR-swizzled source
  const unsigned short* kgb = kb + rowbase * DIMC + h * 64;  // + key*512
  const unsigned short* vgb = vt + (size_t)bh * 64 * NTOK;   // + d*2048 + key
  auto stageK = [&](int buf, int kt) {
#pragma unroll
    for (int i = 0; i < 2; ++i) {
      int off = ((i * 4 + w) << 10) + (lane << 4);  // byte offset in tile
      int row = off >> 7;
      int s16 = ((off >> 4) & 7) ^ (row & 7);
      async_cp16(kgb + (size_t)(kt + row) * DIMC + (s16 << 3),
                 &Kt[buf][0] + (off >> 1));
    }
  };
  auto stageV = [&](int buf, int kt) {
#pragma unroll
    for (int i = 0; i < 2; ++i) {
      int off = ((i * 4 + w) << 10) + (lane << 4);
      int row = off >> 7;
      int s16 = ((off >> 4) & 7) ^ (row & 7);
      async_cp16(vgb + (size_t)row * NTOK + kt + (s16 << 3),
                 &Vt[buf][0] + (off >> 1));
    }
  };

  stageK(0, 0);
  stageV(0, 0);
  __syncthreads();  // drains vmcnt+lgkm (stage 0 + Msk fill)

  float mrun[2] = {-1e30f, -1e30f};
  float lrun[2] = {0.f, 0.f};
  f32x4 oacc[2][4];
#pragma unroll
  for (int qi = 0; qi < 2; ++qi)
#pragma unroll
    for (int f = 0; f < 4; ++f) oacc[qi][f] = f32x4{0.f, 0.f, 0.f, 0.f};

  const int swz = (r & 7) << 4;
  unsigned char* pw = (unsigned char*)&Pt[w][0];

  int cur = 0;
  for (int kt = 0; kt < NTOK; kt += 64) {
    if (kt + 64 < NTOK) {
      stageK(cur ^ 1, kt + 64);
      stageV(cur ^ 1, kt + 64);
    }

    // K fragments from LDS (A-operand: rows=keys)
    const unsigned char* kp = (const unsigned char*)&Kt[cur][0];
    bf16x8 kf[4][2];
#pragma unroll
    for (int f = 0; f < 4; ++f)
#pragma unroll
      for (int ks = 0; ks < 2; ++ks)
        kf[f][ks] = *reinterpret_cast<const bf16x8*>(
            kp + (f * 16 + r) * 128 + ((ks * 64 + g * 16) ^ swz));

    // S^T = K @ Q^T : lane holds keys {f*16+g*4+j} for q-row r
    f32x4 s[2][4];
#pragma unroll
    for (int qi = 0; qi < 2; ++qi)
#pragma unroll
      for (int f = 0; f < 4; ++f) s[qi][f] = f32x4{0.f, 0.f, 0.f, 0.f};
#pragma unroll
    for (int ks = 0; ks < 2; ++ks)
#pragma unroll
      for (int qi = 0; qi < 2; ++qi)
#pragma unroll
        for (int f = 0; f < 4; ++f)
          s[qi][f] = __builtin_amdgcn_mfma_f32_16x16x32_bf16(
              kf[f][ks], aq[qi][ks], s[qi][f], 0, 0, 0);

    // mask + scale (exp2 domain)
#pragma unroll
    for (int f = 0; f < 4; ++f) {
      unsigned mw = *reinterpret_cast<const unsigned*>(&Msk[kt + f * 16 + g * 4]);
#pragma unroll
      for (int j = 0; j < 4; ++j) {
        bool vld = (mw >> (8 * j)) & 0xFFu;
#pragma unroll
        for (int qi = 0; qi < 2; ++qi)
          s[qi][f][j] = vld ? s[qi][f][j] * SCALE2 : MASKV2;
      }
    }

    // online softmax (per lane = one q-row per qi)
    float corr[2];
#pragma unroll
    for (int qi = 0; qi < 2; ++qi) {
      float tm = s[qi][0][0];
#pragma unroll
      for (int f = 0; f < 4; ++f)
#pragma unroll
        for (int j = 0; j < 4; ++j) tm = fmaxf(tm, s[qi][f][j]);
      tm = fmaxf(tm, __shfl_xor(tm, 16));
      tm = fmaxf(tm, __shfl_xor(tm, 32));
      float mnew = fmaxf(mrun[qi], tm);
      corr[qi] = __builtin_exp2f(mrun[qi] - mnew);
      float rs = 0.f;
#pragma unroll
      for (int f = 0; f < 4; ++f)
#pragma unroll
        for (int j = 0; j < 4; ++j) {
          float p = __builtin_exp2f(s[qi][f][j] - mnew);
          s[qi][f][j] = p;
          rs += p;
        }
      rs += __shfl_xor(rs, 16);
      rs += __shfl_xor(rs, 32);
      lrun[qi] = lrun[qi] * corr[qi] + rs;
      mrun[qi] = mnew;
    }

    // rescale oacc: need corr of q-rows g*4+j (held at lane (lane&48)|(g*4+j))
#pragma unroll
    for (int qi = 0; qi < 2; ++qi)
#pragma unroll
      for (int j = 0; j < 4; ++j) {
        float cj = __shfl(corr[qi], (lane & 48) | (g * 4 + j));
#pragma unroll
        for (int f = 0; f < 4; ++f) oacc[qi][f][j] *= cj;
      }

    // write P (packed bf16, swizzled): row=qi*16+r, keys f*16+g*4+0..3
#pragma unroll
    for (int qi = 0; qi < 2; ++qi)
#pragma unroll
      for (int f = 0; f < 4; ++f) {
        unsigned lo = cvtpk(s[qi][f][0], s[qi][f][1]);
        unsigned hi = cvtpk(s[qi][f][2], s[qi][f][3]);
        int boff = (qi * 16 + r) * 128 + ((f * 32 + g * 8) ^ swz);
        *reinterpret_cast<uint2*>(pw + boff) = make_uint2(lo, hi);
      }

    // V fragments + P fragments, PV accumulate
    const unsigned char* vp = (const unsigned char*)&Vt[cur][0];
    bf16x8 vf[4][2];
#pragma unroll
    for (int f = 0; f < 4; ++f)
#pragma unroll
      for (int ks = 0; ks < 2; ++ks)
        vf[f][ks] = *reinterpret_cast<const bf16x8*>(
            vp + (f * 16 + r) * 128 + ((ks * 64 + g * 16) ^ swz));
    bf16x8 pa[2][2];
#pragma unroll
    for (int qi = 0; qi < 2; ++qi)
#pragma unroll
      for (int ks = 0; ks < 2; ++ks)
        pa[qi][ks] = *reinterpret_cast<const bf16x8*>(
            pw + (qi * 16 + r) * 128 + ((ks * 64 + g * 16) ^ swz));
#pragma unroll
    for (int ks = 0; ks < 2; ++ks)
#pragma unroll
      for (int qi = 0; qi < 2; ++qi)
#pragma unroll
        for (int f = 0; f < 4; ++f)
          oacc[qi][f] = __builtin_amdgcn_mfma_f32_16x16x32_bf16(
              pa[qi][ks], vf[f][ks], oacc[qi][f], 0, 0, 0);

    __syncthreads();  // drains prefetch vmcnt; all waves done with buf cur
    cur ^= 1;
  }

  // epilogue: O = q + PV/l
#pragma unroll
  for (int qi = 0; qi < 2; ++qi) {
#pragma unroll
    for (int j = 0; j < 4; ++j) {
      float linv = 1.0f / __shfl(lrun[qi], (lane & 48) | (g * 4 + j));
      int row = q0w + qi * 16 + g * 4 + j;
#pragma unroll
      for (int f = 0; f < 4; ++f) {
        int col = h * 64 + f * 16 + r;
        size_t idx = (rowbase + row) * DIMC + col;
        float o = b2f(qb[idx]) + oacc[qi][f][j] * linv;
        Of32[idx] = o;
        Ob[idx] = f2b(o);
      }
    }
  }
}

extern "C" void kernel_launch(void* const* d_in, const int* in_sizes, int n_in,
                              void* d_out, int out_size, void* d_ws, size_t ws_size,
                              hipStream_t stream) {
  const float* Q  = (const float*)d_in[0];
  const float* V  = (const float*)d_in[1];
  const unsigned char* mask = (const unsigned char*)d_in[2];
  const float* Wq = (const float*)d_in[3];
  const float* bq = (const float*)d_in[4];
  const float* Wk = (const float*)d_in[5];
  const float* bk = (const float*)d_in[6];
  const float* Wv = (const float*)d_in[7];
  const float* bv = (const float*)d_in[8];
  const float* Wo = (const float*)d_in[9];
  const float* bo = (const float*)d_in[10];

  char* ws = (char*)d_ws;
  size_t off = 0;
  auto alloc = [&](size_t bytes) -> void* {
    void* p = ws + off;
    off += (bytes + 255) & ~(size_t)255;
    return p;
  };
  int* flag = (int*)alloc(4);
  unsigned short* Qb  = (unsigned short*)alloc((size_t)MTOK * DIMC * 2);
  unsigned short* Vb  = (unsigned short*)alloc((size_t)MTOK * DIMC * 2);
  unsigned short* Wqb = (unsigned short*)alloc((size_t)DIMC * DIMC * 2);
  unsigned short* Wkb = (unsigned short*)alloc((size_t)DIMC * DIMC * 2);
  unsigned short* Wvb = (unsigned short*)alloc((size_t)DIMC * DIMC * 2);
  unsigned short* Wob = (unsigned short*)alloc((size_t)DIMC * DIMC * 2);
  unsigned short* qbf = (unsigned short*)alloc((size_t)MTOK * DIMC * 2);
  unsigned short* kbf = (unsigned short*)alloc((size_t)MTOK * DIMC * 2);
  unsigned short* vtb = (unsigned short*)alloc((size_t)MTOK * DIMC * 2);
  unsigned short* Obf = (unsigned short*)alloc((size_t)MTOK * DIMC * 2);
  // Of32 (32MB) aliases Qb+Vb (consumed before attention runs)
  float* Of32 = (float*)Qb;

  hipMemsetAsync(flag, 0, 4, stream);
  detect_kernel<<<1, 256, 0, stream>>>(mask, flag);

  const int n4t = MTOK * DIMC / 4;
  cvt_kernel<<<(n4t + 255) / 256, 256, 0, stream>>>(Q, Qb, n4t);
  cvt_kernel<<<(n4t + 255) / 256, 256, 0, stream>>>(V, Vb, n4t);
  const int n4w = DIMC * DIMC / 4;
  cvt_kernel<<<(n4w + 255) / 256, 256, 0, stream>>>(Wq, Wqb, n4w);
  cvt_kernel<<<(n4w + 255) / 256, 256, 0, stream>>>(Wk, Wkb, n4w);
  cvt_kernel<<<(n4w + 255) / 256, 256, 0, stream>>>(Wv, Wvb, n4w);
  cvt_kernel<<<(n4w + 255) / 256, 256, 0, stream>>>(Wo, Wob, n4w);

  dim3 gg(MTOK / 128, DIMC / 128);  // 64 x 4
  gemm_nt<0><<<gg, 256, 0, stream>>>(Qb, Wqb, bq, qbf, nullptr, nullptr);
  gemm_nt<0><<<gg, 256, 0, stream>>>(Vb, Wkb, bk, kbf, nullptr, nullptr);
  gemm_nt<1><<<gg, 256, 0, stream>>>(Vb, Wvb, bv, vtb, nullptr, nullptr);

  attn_kernel<<<dim3(NTOK / 128, BB * 8), 256, 0, stream>>>(
      qbf, kbf, vtb, mask, flag, Of32, Obf);

  gemm_nt<2><<<gg, 256, 0, stream>>>(Obf, Wob, bo, nullptr, Of32, (float*)d_out);
}

// Round 3
// 204.746 us; speedup vs baseline: 2.3608x; 1.0658x over previous
//
#include <hip/hip_runtime.h>

// MAB block: q=QWq^T+bq, k=(VWk^T+bk)*scale, v=VWv^T+bv, 8-head masked
// attention with residual (Oh = qh + A@vh), merge heads,
// out = O + relu(O Wo^T + bo).  B=4, N=2048, DIM=512, HEADS=8, d=64.
// All compute bf16-MFMA with f32 accumulation.

typedef __attribute__((ext_vector_type(8))) __bf16 bf16x8;
typedef __attribute__((ext_vector_type(4))) float f32x4;

#define DEV static __device__ __forceinline__

constexpr int DIMC = 512;
constexpr int NTOK = 2048;
constexpr int BB   = 4;
constexpr int MTOK = BB * NTOK;          // 8192
constexpr float SCALE2 = 0.04419417382415922f * 1.4426950408889634f; // /sqrt(512)*log2(e)
constexpr float MASKV2 = -100.0f * 1.4426950408889634f;  // -100 in exp2 domain

DEV unsigned short f2b(float f) {        // f32 -> bf16 bits, RNE (finite inputs)
  unsigned u = __float_as_uint(f);
  u = (u + 0x7FFFu + ((u >> 16) & 1u)) >> 16;
  return (unsigned short)u;
}
DEV float b2f(unsigned short b) { return __uint_as_float(((unsigned)b) << 16); }

DEV unsigned cvtpk(float a, float b) {   // {lo=bf16(a), hi=bf16(b)}
  unsigned r;
  asm("v_cvt_pk_bf16_f32 %0, %1, %2" : "=v"(r) : "v"(a), "v"(b));
  return r;
}

DEV bf16x8 pack8(unsigned d0, unsigned d1, unsigned d2, unsigned d3) {
  union { unsigned u[4]; bf16x8 v; } t;
  t.u[0] = d0; t.u[1] = d1; t.u[2] = d2; t.u[3] = d3;
  return t.v;
}

DEV void async_cp16(const unsigned short* src, unsigned short* dst) {
  __builtin_amdgcn_global_load_lds(
      (const __attribute__((address_space(1))) void*)(src),
      (__attribute__((address_space(3))) void*)(dst), 16, 0, 0);
}

// ---------------- one-shot f32 -> bf16 conversion: Q, V, 4 weights ----------------
__global__ void cvt_all(const float* __restrict__ Q, const float* __restrict__ V,
                        const float* __restrict__ Wq, const float* __restrict__ Wk,
                        const float* __restrict__ Wv, const float* __restrict__ Wo,
                        unsigned short* __restrict__ Qb, unsigned short* __restrict__ Vb,
                        unsigned short* __restrict__ Wqb, unsigned short* __restrict__ Wkb,
                        unsigned short* __restrict__ Wvb, unsigned short* __restrict__ Wob) {
  int i = blockIdx.x * blockDim.x + threadIdx.x;  // float4 index, total 2359296
  const float* s; unsigned short* d; int off;
  if (i < 2097152) {
    if (i < 1048576) { s = Q; d = Qb; off = i; }
    else             { s = V; d = Vb; off = i - 1048576; }
  } else {
    int k = i - 2097152;
    int wsel = k >> 16;  off = k & 65535;
    s = (wsel == 0) ? Wq : (wsel == 1) ? Wk : (wsel == 2) ? Wv : Wo;
    d = (wsel == 0) ? Wqb : (wsel == 1) ? Wkb : (wsel == 2) ? Wvb : Wob;
  }
  float4 v = reinterpret_cast<const float4*>(s)[off];
  ushort4 o;
  o.x = f2b(v.x); o.y = f2b(v.y); o.z = f2b(v.z); o.w = f2b(v.w);
  reinterpret_cast<ushort4*>(d)[off] = o;
}

// ---------------- mask dtype detection ----------------
__global__ void detect_kernel(const unsigned char* __restrict__ m,
                              int* __restrict__ flag) {
  int any = 0;
  for (int i = threadIdx.x; i < BB * NTOK; i += blockDim.x)
    if ((i & 3) == 1 && m[i]) any = 1;
  if (any) atomicOr(flag, 1);
}

// ---------------- fused projection GEMM ----------------
// grid (12, 128). blockIdx.x>>2 selects region: 0=q, 1=k (scaled), 2=v (transposed).
// Block tile 64 rows x 128 cols; 4 waves (2x2), wave tile 32x64. Direct-global frags.
__global__ __launch_bounds__(256) void proj_gemm(
    const unsigned short* __restrict__ Qb, const unsigned short* __restrict__ Vb,
    const unsigned short* __restrict__ Wqb, const unsigned short* __restrict__ Wkb,
    const unsigned short* __restrict__ Wvb,
    const float* __restrict__ bq, const float* __restrict__ bk,
    const float* __restrict__ bv,
    unsigned short* __restrict__ qbf, unsigned short* __restrict__ kbf,
    unsigned short* __restrict__ vtb) {
  const int region = blockIdx.x >> 2;
  const int colt = blockIdx.x & 3;
  const unsigned short* A = (region == 0) ? Qb : Vb;
  const unsigned short* W = (region == 0) ? Wqb : (region == 1) ? Wkb : Wvb;
  const float* bias = (region == 0) ? bq : (region == 1) ? bk : bv;

  const int lane = threadIdx.x & 63;
  const int w = threadIdx.x >> 6;
  const int r = lane & 15, g = lane >> 4;
  const int row0 = blockIdx.y * 64 + (w >> 1) * 32;
  const int col0 = colt * 128 + (w & 1) * 64;

  f32x4 acc[2][4];
#pragma unroll
  for (int i = 0; i < 2; ++i)
#pragma unroll
    for (int j = 0; j < 4; ++j) acc[i][j] = f32x4{0.f, 0.f, 0.f, 0.f};

#pragma unroll 2
  for (int kk = 0; kk < DIMC; kk += 32) {
    bf16x8 af[2], bw[4];
#pragma unroll
    for (int i = 0; i < 2; ++i)
      af[i] = *reinterpret_cast<const bf16x8*>(
          A + (size_t)(row0 + i * 16 + r) * DIMC + kk + g * 8);
#pragma unroll
    for (int j = 0; j < 4; ++j)
      bw[j] = *reinterpret_cast<const bf16x8*>(
          W + (size_t)(col0 + j * 16 + r) * DIMC + kk + g * 8);
#pragma unroll
    for (int i = 0; i < 2; ++i)
#pragma unroll
      for (int j = 0; j < 4; ++j)
        acc[i][j] = __builtin_amdgcn_mfma_f32_16x16x32_bf16(af[i], bw[j],
                                                            acc[i][j], 0, 0, 0);
  }

#pragma unroll
  for (int i = 0; i < 2; ++i) {
#pragma unroll
    for (int j = 0; j < 4; ++j) {
      const int n = col0 + j * 16 + r;
      const int m0 = row0 + i * 16 + g * 4;
      if (region == 2) {  // v: write transposed per head, pack 4 tokens (8B)
        int bidx = m0 >> 11, t0 = m0 & 2047, h = n >> 6, dd = n & 63;
        ushort4 o;
        o.x = f2b(acc[i][j][0] + bias[n]);
        o.y = f2b(acc[i][j][1] + bias[n]);
        o.z = f2b(acc[i][j][2] + bias[n]);
        o.w = f2b(acc[i][j][3] + bias[n]);
        *reinterpret_cast<ushort4*>(
            vtb + (size_t)((bidx * 8 + h) * 64 + dd) * NTOK + t0) = o;
      } else {
        const float sc = (region == 1) ? SCALE2 : 1.0f;
        unsigned short* dst = (region == 1) ? kbf : qbf;
#pragma unroll
        for (int q = 0; q < 4; ++q) {
          float val = (acc[i][j][q] + bias[n]) * sc;
          dst[(size_t)(m0 + q) * DIMC + n] = f2b(val);
        }
      }
    }
  }
}

// ---------------- output GEMM: out = resid + relu(A Wo^T + bo) ----------------
// grid (4, 128). Block tile 64x128, 4 waves (2x2), wave tile 32x64.
__global__ __launch_bounds__(256) void out_gemm(
    const unsigned short* __restrict__ A, const unsigned short* __restrict__ W,
    const float* __restrict__ bias, const float* __restrict__ resid,
    float* __restrict__ outf) {
  const int lane = threadIdx.x & 63;
  const int w = threadIdx.x >> 6;
  const int r = lane & 15, g = lane >> 4;
  const int row0 = blockIdx.y * 64 + (w >> 1) * 32;
  const int col0 = blockIdx.x * 128 + (w & 1) * 64;

  f32x4 acc[2][4];
#pragma unroll
  for (int i = 0; i < 2; ++i)
#pragma unroll
    for (int j = 0; j < 4; ++j) acc[i][j] = f32x4{0.f, 0.f, 0.f, 0.f};

#pragma unroll 2
  for (int kk = 0; kk < DIMC; kk += 32) {
    bf16x8 af[2], bw[4];
#pragma unroll
    for (int i = 0; i < 2; ++i)
      af[i] = *reinterpret_cast<const bf16x8*>(
          A + (size_t)(row0 + i * 16 + r) * DIMC + kk + g * 8);
#pragma unroll
    for (int j = 0; j < 4; ++j)
      bw[j] = *reinterpret_cast<const bf16x8*>(
          W + (size_t)(col0 + j * 16 + r) * DIMC + kk + g * 8);
#pragma unroll
    for (int i = 0; i < 2; ++i)
#pragma unroll
      for (int j = 0; j < 4; ++j)
        acc[i][j] = __builtin_amdgcn_mfma_f32_16x16x32_bf16(af[i], bw[j],
                                                            acc[i][j], 0, 0, 0);
  }

#pragma unroll
  for (int i = 0; i < 2; ++i)
#pragma unroll
    for (int j = 0; j < 4; ++j) {
      const int n = col0 + j * 16 + r;
#pragma unroll
      for (int q = 0; q < 4; ++q) {
        int m = row0 + i * 16 + g * 4 + q;
        float val = acc[i][j][q] + bias[n];
        outf[(size_t)m * DIMC + n] = resid[(size_t)m * DIMC + n] + fmaxf(val, 0.f);
      }
    }
}

// ---------------- fused masked attention with residual ----------------
// grid (N/64, B*H), 4 waves/block, wave owns 16 q-rows. K/V 64-key tiles
// double-buffered in LDS via global_load_lds with XOR-swizzled source.
// K rows staged sigma-PERMUTED: sigma(16f+4g+j) = 8g+4(f&1)+32(f>>1)+j, so the
// swapped-QK^T D-layout per lane IS the PV A-fragment order: P never leaves
// registers (8 cvt_pk, zero shuffles, zero LDS). k pre-scaled by SCALE2.
__global__ __launch_bounds__(256, 4) void attn_kernel(
    const unsigned short* __restrict__ qb, const unsigned short* __restrict__ kb,
    const unsigned short* __restrict__ vt, const unsigned char* __restrict__ mask8,
    const int* __restrict__ flagp, float* __restrict__ Of32,
    unsigned short* __restrict__ Ob) {
  __shared__ unsigned short Kt[2][64 * 64];   // 8KB each, 128B rows, swizzled
  __shared__ unsigned short Vt[2][64 * 64];
  __shared__ unsigned char Msk[NTOK];

  const int tid = threadIdx.x;
  const int lane = tid & 63;
  const int w = tid >> 6;
  const int r = lane & 15, g = lane >> 4;
  const int bh = blockIdx.y, b = bh >> 3, h = bh & 7;
  const int q0 = blockIdx.x * 64 + w * 16;
  const size_t rowbase = (size_t)b * NTOK;
  const int flag = *flagp;
  const unsigned* mask32 = (const unsigned*)mask8;

  for (int i = tid; i < NTOK; i += 256)
    Msk[i] = (flag ? (unsigned)mask8[b * NTOK + i] : mask32[b * NTOK + i]) ? 1 : 0;

  // Q fragments (B-operand): col=q-row at lane r, k(d)-chunk g*8
  bf16x8 aq[2];
#pragma unroll
  for (int ks = 0; ks < 2; ++ks)
    aq[ks] = *reinterpret_cast<const bf16x8*>(
        qb + (rowbase + q0 + r) * DIMC + h * 64 + ks * 32 + g * 8);

  const unsigned short* kgb = kb + rowbase * DIMC + h * 64;  // + key*512
  const unsigned short* vgb = vt + (size_t)bh * 64 * NTOK;   // + d*2048 + key

  auto stageK = [&](int buf, int kt) {
#pragma unroll
    for (int i = 0; i < 2; ++i) {
      int off = ((i * 4 + w) << 10) + (lane << 4);  // byte offset in 8KB tile
      int row = off >> 7;                           // K-position 0..63
      int s16 = ((off >> 4) & 7) ^ (row & 7);       // swizzled 16B slot
      int f = row >> 4, gg = (row >> 2) & 3, j = row & 3;
      int tok = 8 * gg + 4 * (f & 1) + 32 * (f >> 1) + j;   // sigma(row)
      async_cp16(kgb + (size_t)(kt + tok) * DIMC + (s16 << 3),
                 &Kt[buf][0] + (off >> 1));
    }
  };
  auto stageV = [&](int buf, int kt) {
#pragma unroll
    for (int i = 0; i < 2; ++i) {
      int off = ((i * 4 + w) << 10) + (lane << 4);
      int row = off >> 7;                           // d 0..63, tokens natural
      int s16 = ((off >> 4) & 7) ^ (row & 7);
      async_cp16(vgb + (size_t)row * NTOK + kt + (s16 << 3),
                 &Vt[buf][0] + (off >> 1));
    }
  };

  stageK(0, 0);
  stageV(0, 0);
  __syncthreads();

  float mrun = -1e30f, lrun = 0.f;
  f32x4 oacc[4];
#pragma unroll
  for (int f = 0; f < 4; ++f) oacc[f] = f32x4{0.f, 0.f, 0.f, 0.f};

  const int swz = (r & 7) << 4;
  int cur = 0;
  for (int kt = 0; kt < NTOK; kt += 64) {
    if (kt + 64 < NTOK) {
      stageK(cur ^ 1, kt + 64);
      stageV(cur ^ 1, kt + 64);
    }

    // QK^T (swapped): s[f] reg j at lane (g,r) = S[token kt+sigma(16f+4g+j)][q0+r]
    const unsigned char* kp = (const unsigned char*)&Kt[cur][0];
    f32x4 s[4];
#pragma unroll
    for (int f = 0; f < 4; ++f) s[f] = f32x4{0.f, 0.f, 0.f, 0.f};
    __builtin_amdgcn_s_setprio(1);
#pragma unroll
    for (int ks = 0; ks < 2; ++ks)
#pragma unroll
      for (int f = 0; f < 4; ++f) {
        bf16x8 kf = *reinterpret_cast<const bf16x8*>(
            kp + (f * 16 + r) * 128 + ((ks * 64 + g * 16) ^ swz));
        s[f] = __builtin_amdgcn_mfma_f32_16x16x32_bf16(kf, aq[ks], s[f], 0, 0, 0);
      }
    __builtin_amdgcn_s_setprio(0);

    // mask (k pre-scaled; masked logits exactly -100 in exp2 domain)
#pragma unroll
    for (int f = 0; f < 4; ++f) {
      int tb = kt + 8 * g + 4 * (f & 1) + 32 * (f >> 1);
      unsigned mw = *reinterpret_cast<const unsigned*>(&Msk[tb]);
#pragma unroll
      for (int j = 0; j < 4; ++j)
        if (!((mw >> (8 * j)) & 0xFFu)) s[f][j] = MASKV2;
    }

    // online softmax: lane owns 16 keys of q-row r; reduce over g-groups
    float tm = s[0][0];
#pragma unroll
    for (int f = 0; f < 4; ++f)
#pragma unroll
      for (int j = 0; j < 4; ++j) tm = fmaxf(tm, s[f][j]);
    tm = fmaxf(tm, __shfl_xor(tm, 16));
    tm = fmaxf(tm, __shfl_xor(tm, 32));
    if (!__all(tm <= mrun + 8.f)) {       // defer-max: rescale only when needed
      float mnew = fmaxf(mrun, tm);
      float corr = __builtin_exp2f(mrun - mnew);
      lrun *= corr;
      mrun = mnew;
#pragma unroll
      for (int j = 0; j < 4; ++j) {
        float cj = __shfl(corr, (lane & 48) | (g * 4 + j));
#pragma unroll
        for (int f = 0; f < 4; ++f) oacc[f][j] *= cj;
      }
    }
    float rs = 0.f;
#pragma unroll
    for (int f = 0; f < 4; ++f)
#pragma unroll
      for (int j = 0; j < 4; ++j) {
        float p = __builtin_exp2f(s[f][j] - mrun);
        s[f][j] = p;
        rs += p;
      }
    rs += __shfl_xor(rs, 16);
    rs += __shfl_xor(rs, 32);
    lrun += rs;

    // P -> PV A-fragments, fully in-register (sigma makes the order line up)
    bf16x8 pa[2];
#pragma unroll
    for (int ks = 0; ks < 2; ++ks)
      pa[ks] = pack8(cvtpk(s[2 * ks][0], s[2 * ks][1]),
                     cvtpk(s[2 * ks][2], s[2 * ks][3]),
                     cvtpk(s[2 * ks + 1][0], s[2 * ks + 1][1]),
                     cvtpk(s[2 * ks + 1][2], s[2 * ks + 1][3]));

    // PV: oacc[f] (cols d=f*16+r, rows q=g*4+j) += P @ V
    const unsigned char* vp = (const unsigned char*)&Vt[cur][0];
    __builtin_amdgcn_s_setprio(1);
#pragma unroll
    for (int ks = 0; ks < 2; ++ks)
#pragma unroll
      for (int f = 0; f < 4; ++f) {
        bf16x8 vf = *reinterpret_cast<const bf16x8*>(
            vp + (f * 16 + r) * 128 + ((ks * 64 + g * 16) ^ swz));
        oacc[f] = __builtin_amdgcn_mfma_f32_16x16x32_bf16(pa[ks], vf, oacc[f], 0, 0, 0);
      }
    __builtin_amdgcn_s_setprio(0);

    __syncthreads();  // drains prefetch vmcnt; all waves done with buf cur
    cur ^= 1;
  }

  // epilogue: O = q + PV/l  (oacc row = q-row g*4+j, col = d f*16+r)
#pragma unroll
  for (int j = 0; j < 4; ++j) {
    float linv = 1.0f / __shfl(lrun, (lane & 48) | (g * 4 + j));
    int row = q0 + g * 4 + j;
#pragma unroll
    for (int f = 0; f < 4; ++f) {
      int col = h * 64 + f * 16 + r;
      size_t idx = (rowbase + row) * DIMC + col;
      float o = b2f(qb[idx]) + oacc[f][j] * linv;
      Of32[idx] = o;
      Ob[idx] = f2b(o);
    }
  }
}

extern "C" void kernel_launch(void* const* d_in, const int* in_sizes, int n_in,
                              void* d_out, int out_size, void* d_ws, size_t ws_size,
                              hipStream_t stream) {
  const float* Q  = (const float*)d_in[0];
  const float* V  = (const float*)d_in[1];
  const unsigned char* mask = (const unsigned char*)d_in[2];
  const float* Wq = (const float*)d_in[3];
  const float* bq = (const float*)d_in[4];
  const float* Wk = (const float*)d_in[5];
  const float* bk = (const float*)d_in[6];
  const float* Wv = (const float*)d_in[7];
  const float* bv = (const float*)d_in[8];
  const float* Wo = (const float*)d_in[9];
  const float* bo = (const float*)d_in[10];

  char* ws = (char*)d_ws;
  size_t off = 0;
  auto alloc = [&](size_t bytes) -> void* {
    void* p = ws + off;
    off += (bytes + 255) & ~(size_t)255;
    return p;
  };
  int* flag = (int*)alloc(4);
  unsigned short* Qb  = (unsigned short*)alloc((size_t)MTOK * DIMC * 2);
  unsigned short* Vb  = (unsigned short*)alloc((size_t)MTOK * DIMC * 2);
  unsigned short* Wqb = (unsigned short*)alloc((size_t)DIMC * DIMC * 2);
  unsigned short* Wkb = (unsigned short*)alloc((size_t)DIMC * DIMC * 2);
  unsigned short* Wvb = (unsigned short*)alloc((size_t)DIMC * DIMC * 2);
  unsigned short* Wob = (unsigned short*)alloc((size_t)DIMC * DIMC * 2);
  unsigned short* qbf = (unsigned short*)alloc((size_t)MTOK * DIMC * 2);
  unsigned short* kbf = (unsigned short*)alloc((size_t)MTOK * DIMC * 2);
  unsigned short* vtb = (unsigned short*)alloc((size_t)MTOK * DIMC * 2);
  unsigned short* Obf = (unsigned short*)alloc((size_t)MTOK * DIMC * 2);
  // Of32 (32MB f32) aliases Qb+Vb (both consumed by proj_gemm before attention)
  float* Of32 = (float*)Qb;

  hipMemsetAsync(flag, 0, 4, stream);
  detect_kernel<<<1, 256, 0, stream>>>(mask, flag);

  cvt_all<<<9216, 256, 0, stream>>>(Q, V, Wq, Wk, Wv, Wo,
                                    Qb, Vb, Wqb, Wkb, Wvb, Wob);

  proj_gemm<<<dim3(12, MTOK / 64), 256, 0, stream>>>(
      Qb, Vb, Wqb, Wkb, Wvb, bq, bk, bv, qbf, kbf, vtb);

  attn_kernel<<<dim3(NTOK / 64, BB * 8), 256, 0, stream>>>(
      qbf, kbf, vtb, mask, flag, Of32, Obf);

  out_gemm<<<dim3(4, MTOK / 64), 256, 0, stream>>>(
      Obf, Wob, bo, Of32, (float*)d_out);
}

// Round 4
// 153.785 us; speedup vs baseline: 3.1431x; 1.3314x over previous
//
#include <hip/hip_runtime.h>

// MAB block: q=QWq^T+bq, k=(VWk^T+bk)*scale, v=VWv^T+bv, 8-head masked
// attention with residual (Oh = qh + A@vh), merge heads,
// out = O + relu(O Wo^T + bo).  B=4, N=2048, DIM=512, HEADS=8, d=64.
// All compute bf16-MFMA with f32 accumulation.

typedef __attribute__((ext_vector_type(8))) __bf16 bf16x8;
typedef __attribute__((ext_vector_type(4))) float f32x4;

#define DEV static __device__ __forceinline__

constexpr int DIMC = 512;
constexpr int NTOK = 2048;
constexpr int BB   = 4;
constexpr int MTOK = BB * NTOK;          // 8192
constexpr float SCALE2 = 0.04419417382415922f * 1.4426950408889634f; // /sqrt(512)*log2(e)
constexpr float MASKV2 = -100.0f * 1.4426950408889634f;  // -100 in exp2 domain

DEV unsigned short f2b(float f) {        // f32 -> bf16 bits, RNE (finite inputs)
  unsigned u = __float_as_uint(f);
  u = (u + 0x7FFFu + ((u >> 16) & 1u)) >> 16;
  return (unsigned short)u;
}
DEV float b2f(unsigned short b) { return __uint_as_float(((unsigned)b) << 16); }

DEV unsigned cvtpk(float a, float b) {   // {lo=bf16(a), hi=bf16(b)}
  unsigned r;
  asm("v_cvt_pk_bf16_f32 %0, %1, %2" : "=v"(r) : "v"(a), "v"(b));
  return r;
}

DEV bf16x8 pack8(unsigned d0, unsigned d1, unsigned d2, unsigned d3) {
  union { unsigned u[4]; bf16x8 v; } t;
  t.u[0] = d0; t.u[1] = d1; t.u[2] = d2; t.u[3] = d3;
  return t.v;
}

DEV void async_cp16(const void* src, void* dst) {
  __builtin_amdgcn_global_load_lds(
      (const __attribute__((address_space(1))) void*)(src),
      (__attribute__((address_space(3))) void*)(dst), 16, 0, 0);
}

// ------------- f32 -> bf16 conversion (Q, V, 4 weights) + mask detect -------------
__global__ void cvt_all(const float* __restrict__ Q, const float* __restrict__ V,
                        const float* __restrict__ Wq, const float* __restrict__ Wk,
                        const float* __restrict__ Wv, const float* __restrict__ Wo,
                        unsigned short* __restrict__ Qb, unsigned short* __restrict__ Vb,
                        unsigned short* __restrict__ Wqb, unsigned short* __restrict__ Wkb,
                        unsigned short* __restrict__ Wvb, unsigned short* __restrict__ Wob,
                        const unsigned char* __restrict__ mask, int* __restrict__ flag) {
  if (blockIdx.x == 9216) {  // mask dtype detect: bool(1B) vs int/float(4B 0/1)
    int any = 0;
    for (int i = threadIdx.x; i < BB * NTOK; i += blockDim.x)
      if ((i & 3) == 1 && mask[i]) any = 1;
    if (any) atomicOr(flag, 1);
    return;
  }
  int i = blockIdx.x * blockDim.x + threadIdx.x;  // float4 index, total 2359296
  const float* s; unsigned short* d; int off;
  if (i < 2097152) {
    if (i < 1048576) { s = Q; d = Qb; off = i; }
    else             { s = V; d = Vb; off = i - 1048576; }
  } else {
    int k = i - 2097152;
    int wsel = k >> 16;  off = k & 65535;
    s = (wsel == 0) ? Wq : (wsel == 1) ? Wk : (wsel == 2) ? Wv : Wo;
    d = (wsel == 0) ? Wqb : (wsel == 1) ? Wkb : (wsel == 2) ? Wvb : Wob;
  }
  float4 v = reinterpret_cast<const float4*>(s)[off];
  ushort4 o;
  o.x = f2b(v.x); o.y = f2b(v.y); o.z = f2b(v.z); o.w = f2b(v.w);
  reinterpret_cast<ushort4*>(d)[off] = o;
}

// ---------------- fused projection GEMM (LDS-staged, 128x128, BK=32) ----------------
// grid (4 colt, 64 rowt, 3 region): region 0=q, 1=k(scaled), 2=v(transposed to [d][tok]).
// 4 waves (2x2), wave tile 64x64 (4x4 frags). Double-buffered LDS staging via
// global_load_lds w16, XOR-swizzled source (chunk ^= row&3) for conflict-light reads.
__global__ __launch_bounds__(256) void proj_gemm(
    const unsigned short* __restrict__ Qb, const unsigned short* __restrict__ Vb,
    const unsigned short* __restrict__ Wqb, const unsigned short* __restrict__ Wkb,
    const unsigned short* __restrict__ Wvb,
    const float* __restrict__ bq, const float* __restrict__ bk,
    const float* __restrict__ bv,
    unsigned short* __restrict__ qbf, unsigned short* __restrict__ kbf,
    unsigned short* __restrict__ vtb) {
  __shared__ union {
    struct { unsigned short A[2][4096]; unsigned short B[2][4096]; } s;  // 32KB
    unsigned short LT[128 * 136];                                        // 34816B
  } lds;

  const int region = blockIdx.z;
  const unsigned short* A = (region == 0) ? Qb : Vb;
  const unsigned short* W = (region == 0) ? Wqb : (region == 1) ? Wkb : Wvb;
  const float* bias = (region == 0) ? bq : (region == 1) ? bk : bv;

  const int tid = threadIdx.x;
  const int lane = tid & 63;
  const int w = tid >> 6;
  const int r = lane & 15, g = lane >> 4;
  const int rowB = blockIdx.y * 128;           // block row (token) base
  const int colB = blockIdx.x * 128;           // block col (dv) base
  const int rw = (w >> 1) * 64, cw = (w & 1) * 64;  // wave offsets in block tile

  // stage one 128x32 bf16 tile (rows of 64B, chunk^=row&3) into LDS
  auto stage = [&](unsigned short* dst, const unsigned short* srcRow0, int kk) {
#pragma unroll
    for (int i = 0; i < 2; ++i) {
      int off = i * 4096 + tid * 16;           // byte offset in 8KB tile
      int row = off >> 6;
      int c = ((off >> 4) & 3) ^ (row & 3);
      async_cp16(srcRow0 + (size_t)row * DIMC + kk + c * 8, (char*)dst + off);
    }
  };

  f32x4 acc[4][4];
#pragma unroll
  for (int i = 0; i < 4; ++i)
#pragma unroll
    for (int j = 0; j < 4; ++j) acc[i][j] = f32x4{0.f, 0.f, 0.f, 0.f};

  stage(lds.s.A[0], A + (size_t)rowB * DIMC, 0);
  stage(lds.s.B[0], W + (size_t)colB * DIMC, 0);
  __syncthreads();

  int cur = 0;
  for (int kk = 0; kk < DIMC; kk += 32) {
    if (kk + 32 < DIMC) {
      stage(lds.s.A[cur ^ 1], A + (size_t)rowB * DIMC, kk + 32);
      stage(lds.s.B[cur ^ 1], W + (size_t)colB * DIMC, kk + 32);
    }
    const char* ap = (const char*)lds.s.A[cur];
    const char* bp = (const char*)lds.s.B[cur];
    bf16x8 af[4], bw[4];
#pragma unroll
    for (int i = 0; i < 4; ++i) {
      int row = rw + i * 16 + r;
      af[i] = *reinterpret_cast<const bf16x8*>(ap + row * 64 + ((g ^ (row & 3)) * 16));
    }
#pragma unroll
    for (int j = 0; j < 4; ++j) {
      int row = cw + j * 16 + r;
      bw[j] = *reinterpret_cast<const bf16x8*>(bp + row * 64 + ((g ^ (row & 3)) * 16));
    }
    __builtin_amdgcn_s_setprio(1);
#pragma unroll
    for (int i = 0; i < 4; ++i)
#pragma unroll
      for (int j = 0; j < 4; ++j)
        acc[i][j] = __builtin_amdgcn_mfma_f32_16x16x32_bf16(af[i], bw[j],
                                                            acc[i][j], 0, 0, 0);
    __builtin_amdgcn_s_setprio(0);
    __syncthreads();
    cur ^= 1;
  }

  if (region != 2) {  // q / k: natural [tok][dv] bf16 store
    const float sc = (region == 1) ? SCALE2 : 1.0f;
    unsigned short* dst = (region == 1) ? kbf : qbf;
#pragma unroll
    for (int i = 0; i < 4; ++i)
#pragma unroll
      for (int j = 0; j < 4; ++j) {
        int n = colB + cw + j * 16 + r;
        float bn = bias[n];
#pragma unroll
        for (int q = 0; q < 4; ++q) {
          int m = rowB + rw + i * 16 + g * 4 + q;
          dst[(size_t)m * DIMC + n] = f2b((acc[i][j][q] + bn) * sc);
        }
      }
  } else {  // v: transpose 128x128 through LDS, store dense [d][tok] rows
#pragma unroll
    for (int i = 0; i < 4; ++i)
#pragma unroll
      for (int j = 0; j < 4; ++j) {
        int nl = cw + j * 16 + r;             // local dv 0..127
        float bn = bias[colB + nl];
        int tl = rw + i * 16 + g * 4;         // local token base (mult of 4)
        ushort4 o;
        o.x = f2b(acc[i][j][0] + bn);
        o.y = f2b(acc[i][j][1] + bn);
        o.z = f2b(acc[i][j][2] + bn);
        o.w = f2b(acc[i][j][3] + bn);
        *reinterpret_cast<ushort4*>(&lds.LT[nl * 136 + tl]) = o;
      }
    __syncthreads();
    int bidx = rowB >> 11, t0 = rowB & 2047;
#pragma unroll
    for (int rd = 0; rd < 8; ++rd) {
      int idx = rd * 256 + tid;               // 128 dv x 16 chunks
      int dv = idx >> 4, ch = idx & 15;
      int gdv = colB + dv, h = gdv >> 6, dd = gdv & 63;
      ushort4 v0 = *reinterpret_cast<const ushort4*>(&lds.LT[dv * 136 + ch * 8]);
      ushort4 v1 = *reinterpret_cast<const ushort4*>(&lds.LT[dv * 136 + ch * 8 + 4]);
      unsigned short* dst = vtb + (size_t)((bidx * 8 + h) * 64 + dd) * NTOK + t0 + ch * 8;
      reinterpret_cast<ushort4*>(dst)[0] = v0;
      reinterpret_cast<ushort4*>(dst)[1] = v1;
    }
  }
}

// ---------------- output GEMM: out = resid + relu(bf16(O) Wo^T + bo) ----------------
// grid (4, 128). Block tile 64x128, BK=32; A staged as f32 from Of32, converted
// in-register (cvt_pk) to bf16 fragments. 4 waves (2x2), wave tile 32x64.
__global__ __launch_bounds__(256) void out_gemm(
    const float* __restrict__ Of32, const unsigned short* __restrict__ W,
    const float* __restrict__ bias, float* __restrict__ outf) {
  __shared__ struct { float A[2][2048]; unsigned short B[2][4096]; } lds;  // 32KB

  const int tid = threadIdx.x;
  const int lane = tid & 63;
  const int w = tid >> 6;
  const int r = lane & 15, g = lane >> 4;
  const int rowB = blockIdx.y * 64;
  const int colB = blockIdx.x * 128;
  const int rw = (w >> 1) * 32, cw = (w & 1) * 64;

  auto stageA = [&](float* dst, int kk) {  // 64 rows x 32 f32, 128B rows, c^=row&7
    int off = tid * 16;                    // 4KB per round, 2 rounds = 8KB
#pragma unroll
    for (int i = 0; i < 2; ++i) {
      int o2 = off + i * 4096;
      int row = o2 >> 7;
      int c = ((o2 >> 4) & 7) ^ (row & 7);
      async_cp16(Of32 + (size_t)(rowB + row) * DIMC + kk + c * 4, (char*)dst + o2);
    }
  };
  auto stageB = [&](unsigned short* dst, int kk) {  // 128 x 32 bf16
#pragma unroll
    for (int i = 0; i < 2; ++i) {
      int off = i * 4096 + tid * 16;
      int row = off >> 6;
      int c = ((off >> 4) & 3) ^ (row & 3);
      async_cp16(W + (size_t)(colB + row) * DIMC + kk + c * 8, (char*)dst + off);
    }
  };

  f32x4 acc[2][4];
#pragma unroll
  for (int i = 0; i < 2; ++i)
#pragma unroll
    for (int j = 0; j < 4; ++j) acc[i][j] = f32x4{0.f, 0.f, 0.f, 0.f};

  stageA(lds.A[0], 0);
  stageB(lds.B[0], 0);
  __syncthreads();

  int cur = 0;
  for (int kk = 0; kk < DIMC; kk += 32) {
    if (kk + 32 < DIMC) {
      stageA(lds.A[cur ^ 1], kk + 32);
      stageB(lds.B[cur ^ 1], kk + 32);
    }
    const char* ap = (const char*)lds.A[cur];
    const char* bp = (const char*)lds.B[cur];
    bf16x8 af[2], bw[4];
#pragma unroll
    for (int i = 0; i < 2; ++i) {
      int row = rw + i * 16 + r;
      f32x4 lo = *reinterpret_cast<const f32x4*>(
          ap + row * 128 + (((2 * g) ^ (row & 7)) * 16));
      f32x4 hi = *reinterpret_cast<const f32x4*>(
          ap + row * 128 + (((2 * g + 1) ^ (row & 7)) * 16));
      af[i] = pack8(cvtpk(lo[0], lo[1]), cvtpk(lo[2], lo[3]),
                    cvtpk(hi[0], hi[1]), cvtpk(hi[2], hi[3]));
    }
#pragma unroll
    for (int j = 0; j < 4; ++j) {
      int row = cw + j * 16 + r;
      bw[j] = *reinterpret_cast<const bf16x8*>(bp + row * 64 + ((g ^ (row & 3)) * 16));
    }
    __builtin_amdgcn_s_setprio(1);
#pragma unroll
    for (int i = 0; i < 2; ++i)
#pragma unroll
      for (int j = 0; j < 4; ++j)
        acc[i][j] = __builtin_amdgcn_mfma_f32_16x16x32_bf16(af[i], bw[j],
                                                            acc[i][j], 0, 0, 0);
    __builtin_amdgcn_s_setprio(0);
    __syncthreads();
    cur ^= 1;
  }

#pragma unroll
  for (int i = 0; i < 2; ++i)
#pragma unroll
    for (int j = 0; j < 4; ++j) {
      int n = colB + cw + j * 16 + r;
      float bn = bias[n];
#pragma unroll
      for (int q = 0; q < 4; ++q) {
        int m = rowB + rw + i * 16 + g * 4 + q;
        float val = acc[i][j][q] + bn;
        outf[(size_t)m * DIMC + n] = Of32[(size_t)m * DIMC + n] + fmaxf(val, 0.f);
      }
    }
}

// ---------------- fused masked attention with residual ----------------
// grid (N/64, B*H), 4 waves/block, wave owns 16 q-rows. K/V 64-key tiles
// double-buffered in LDS via global_load_lds with XOR-swizzled source.
// K rows staged sigma-PERMUTED: sigma(16f+4g+j) = 8g+4(f&1)+32(f>>1)+j, so the
// swapped-QK^T D-layout per lane IS the PV A-fragment order: P never leaves
// registers (8 cvt_pk, zero shuffles, zero LDS). k pre-scaled by SCALE2.
__global__ __launch_bounds__(256, 4) void attn_kernel(
    const unsigned short* __restrict__ qb, const unsigned short* __restrict__ kb,
    const unsigned short* __restrict__ vt, const unsigned char* __restrict__ mask8,
    const int* __restrict__ flagp, float* __restrict__ Of32) {
  __shared__ unsigned short Kt[2][64 * 64];   // 8KB each, 128B rows, swizzled
  __shared__ unsigned short Vt[2][64 * 64];
  __shared__ unsigned char Msk[NTOK];

  const int tid = threadIdx.x;
  const int lane = tid & 63;
  const int w = tid >> 6;
  const int r = lane & 15, g = lane >> 4;
  const int bh = blockIdx.y, b = bh >> 3, h = bh & 7;
  const int q0 = blockIdx.x * 64 + w * 16;
  const size_t rowbase = (size_t)b * NTOK;
  const int flag = *flagp;
  const unsigned* mask32 = (const unsigned*)mask8;

  for (int i = tid; i < NTOK; i += 256)
    Msk[i] = (flag ? (unsigned)mask8[b * NTOK + i] : mask32[b * NTOK + i]) ? 1 : 0;

  // Q fragments (B-operand): col=q-row at lane r, k(d)-chunk g*8
  bf16x8 aq[2];
#pragma unroll
  for (int ks = 0; ks < 2; ++ks)
    aq[ks] = *reinterpret_cast<const bf16x8*>(
        qb + (rowbase + q0 + r) * DIMC + h * 64 + ks * 32 + g * 8);

  const unsigned short* kgb = kb + rowbase * DIMC + h * 64;  // + key*512
  const unsigned short* vgb = vt + (size_t)bh * 64 * NTOK;   // + d*2048 + key

  auto stageK = [&](int buf, int kt) {
#pragma unroll
    for (int i = 0; i < 2; ++i) {
      int off = ((i * 4 + w) << 10) + (lane << 4);  // byte offset in 8KB tile
      int row = off >> 7;                           // K-position 0..63
      int s16 = ((off >> 4) & 7) ^ (row & 7);       // swizzled 16B slot
      int f = row >> 4, gg = (row >> 2) & 3, j = row & 3;
      int tok = 8 * gg + 4 * (f & 1) + 32 * (f >> 1) + j;   // sigma(row)
      async_cp16(kgb + (size_t)(kt + tok) * DIMC + (s16 << 3),
                 &Kt[buf][0] + (off >> 1));
    }
  };
  auto stageV = [&](int buf, int kt) {
#pragma unroll
    for (int i = 0; i < 2; ++i) {
      int off = ((i * 4 + w) << 10) + (lane << 4);
      int row = off >> 7;                           // d 0..63, tokens natural
      int s16 = ((off >> 4) & 7) ^ (row & 7);
      async_cp16(vgb + (size_t)row * NTOK + kt + (s16 << 3),
                 &Vt[buf][0] + (off >> 1));
    }
  };

  stageK(0, 0);
  stageV(0, 0);
  __syncthreads();

  float mrun = -1e30f, lrun = 0.f;
  f32x4 oacc[4];
#pragma unroll
  for (int f = 0; f < 4; ++f) oacc[f] = f32x4{0.f, 0.f, 0.f, 0.f};

  const int swz = (r & 7) << 4;
  int cur = 0;
  for (int kt = 0; kt < NTOK; kt += 64) {
    if (kt + 64 < NTOK) {
      stageK(cur ^ 1, kt + 64);
      stageV(cur ^ 1, kt + 64);
    }

    // QK^T (swapped): s[f] reg j at lane (g,r) = S[token kt+sigma(16f+4g+j)][q0+r]
    const unsigned char* kp = (const unsigned char*)&Kt[cur][0];
    f32x4 s[4];
#pragma unroll
    for (int f = 0; f < 4; ++f) s[f] = f32x4{0.f, 0.f, 0.f, 0.f};
    __builtin_amdgcn_s_setprio(1);
#pragma unroll
    for (int ks = 0; ks < 2; ++ks)
#pragma unroll
      for (int f = 0; f < 4; ++f) {
        bf16x8 kf = *reinterpret_cast<const bf16x8*>(
            kp + (f * 16 + r) * 128 + ((ks * 64 + g * 16) ^ swz));
        s[f] = __builtin_amdgcn_mfma_f32_16x16x32_bf16(kf, aq[ks], s[f], 0, 0, 0);
      }
    __builtin_amdgcn_s_setprio(0);

    // mask (k pre-scaled; masked logits exactly -100 in exp2 domain)
#pragma unroll
    for (int f = 0; f < 4; ++f) {
      int tb = kt + 8 * g + 4 * (f & 1) + 32 * (f >> 1);
      unsigned mw = *reinterpret_cast<const unsigned*>(&Msk[tb]);
#pragma unroll
      for (int j = 0; j < 4; ++j)
        if (!((mw >> (8 * j)) & 0xFFu)) s[f][j] = MASKV2;
    }

    // online softmax: lane owns 16 keys of q-row r; reduce over g-groups
    float tm = s[0][0];
#pragma unroll
    for (int f = 0; f < 4; ++f)
#pragma unroll
      for (int j = 0; j < 4; ++j) tm = fmaxf(tm, s[f][j]);
    tm = fmaxf(tm, __shfl_xor(tm, 16));
    tm = fmaxf(tm, __shfl_xor(tm, 32));
    if (!__all(tm <= mrun + 8.f)) {       // defer-max: rescale only when needed
      float mnew = fmaxf(mrun, tm);
      float corr = __builtin_exp2f(mrun - mnew);
      lrun *= corr;
      mrun = mnew;
#pragma unroll
      for (int j = 0; j < 4; ++j) {
        float cj = __shfl(corr, (lane & 48) | (g * 4 + j));
#pragma unroll
        for (int f = 0; f < 4; ++f) oacc[f][j] *= cj;
      }
    }
    float rs = 0.f;
#pragma unroll
    for (int f = 0; f < 4; ++f)
#pragma unroll
      for (int j = 0; j < 4; ++j) {
        float p = __builtin_exp2f(s[f][j] - mrun);
        s[f][j] = p;
        rs += p;
      }
    rs += __shfl_xor(rs, 16);
    rs += __shfl_xor(rs, 32);
    lrun += rs;

    // P -> PV A-fragments, fully in-register (sigma makes the order line up)
    bf16x8 pa[2];
#pragma unroll
    for (int ks = 0; ks < 2; ++ks)
      pa[ks] = pack8(cvtpk(s[2 * ks][0], s[2 * ks][1]),
                     cvtpk(s[2 * ks][2], s[2 * ks][3]),
                     cvtpk(s[2 * ks + 1][0], s[2 * ks + 1][1]),
                     cvtpk(s[2 * ks + 1][2], s[2 * ks + 1][3]));

    // PV: oacc[f] (cols d=f*16+r, rows q=g*4+j) += P @ V
    const unsigned char* vp = (const unsigned char*)&Vt[cur][0];
    __builtin_amdgcn_s_setprio(1);
#pragma unroll
    for (int ks = 0; ks < 2; ++ks)
#pragma unroll
      for (int f = 0; f < 4; ++f) {
        bf16x8 vf = *reinterpret_cast<const bf16x8*>(
            vp + (f * 16 + r) * 128 + ((ks * 64 + g * 16) ^ swz));
        oacc[f] = __builtin_amdgcn_mfma_f32_16x16x32_bf16(pa[ks], vf, oacc[f], 0, 0, 0);
      }
    __builtin_amdgcn_s_setprio(0);

    __syncthreads();  // drains prefetch vmcnt; all waves done with buf cur
    cur ^= 1;
  }

  // epilogue: O = q + PV/l  (oacc row = q-row g*4+j, col = d f*16+r)
#pragma unroll
  for (int j = 0; j < 4; ++j) {
    float linv = 1.0f / __shfl(lrun, (lane & 48) | (g * 4 + j));
    int row = q0 + g * 4 + j;
#pragma unroll
    for (int f = 0; f < 4; ++f) {
      int col = h * 64 + f * 16 + r;
      size_t idx = (rowbase + row) * DIMC + col;
      Of32[idx] = b2f(qb[idx]) + oacc[f][j] * linv;
    }
  }
}

extern "C" void kernel_launch(void* const* d_in, const int* in_sizes, int n_in,
                              void* d_out, int out_size, void* d_ws, size_t ws_size,
                              hipStream_t stream) {
  const float* Q  = (const float*)d_in[0];
  const float* V  = (const float*)d_in[1];
  const unsigned char* mask = (const unsigned char*)d_in[2];
  const float* Wq = (const float*)d_in[3];
  const float* bq = (const float*)d_in[4];
  const float* Wk = (const float*)d_in[5];
  const float* bk = (const float*)d_in[6];
  const float* Wv = (const float*)d_in[7];
  const float* bv = (const float*)d_in[8];
  const float* Wo = (const float*)d_in[9];
  const float* bo = (const float*)d_in[10];

  char* ws = (char*)d_ws;
  size_t off = 0;
  auto alloc = [&](size_t bytes) -> void* {
    void* p = ws + off;
    off += (bytes + 255) & ~(size_t)255;
    return p;
  };
  int* flag = (int*)alloc(4);
  unsigned short* Qb  = (unsigned short*)alloc((size_t)MTOK * DIMC * 2);
  unsigned short* Vb  = (unsigned short*)alloc((size_t)MTOK * DIMC * 2);
  unsigned short* Wqb = (unsigned short*)alloc((size_t)DIMC * DIMC * 2);
  unsigned short* Wkb = (unsigned short*)alloc((size_t)DIMC * DIMC * 2);
  unsigned short* Wvb = (unsigned short*)alloc((size_t)DIMC * DIMC * 2);
  unsigned short* Wob = (unsigned short*)alloc((size_t)DIMC * DIMC * 2);
  unsigned short* qbf = (unsigned short*)alloc((size_t)MTOK * DIMC * 2);
  unsigned short* kbf = (unsigned short*)alloc((size_t)MTOK * DIMC * 2);
  unsigned short* vtb = (unsigned short*)alloc((size_t)MTOK * DIMC * 2);
  // Of32 (16MB f32) aliases Qb+Vb (both consumed by proj_gemm before attention)
  float* Of32 = (float*)Qb;

  hipMemsetAsync(flag, 0, 4, stream);

  cvt_all<<<9217, 256, 0, stream>>>(Q, V, Wq, Wk, Wv, Wo,
                                    Qb, Vb, Wqb, Wkb, Wvb, Wob, mask, flag);

  proj_gemm<<<dim3(4, MTOK / 128, 3), 256, 0, stream>>>(
      Qb, Vb, Wqb, Wkb, Wvb, bq, bk, bv, qbf, kbf, vtb);

  attn_kernel<<<dim3(NTOK / 64, BB * 8), 256, 0, stream>>>(
      qbf, kbf, vtb, mask, flag, Of32);

  out_gemm<<<dim3(4, MTOK / 64), 256, 0, stream>>>(
      Of32, Wob, bo, (float*)d_out);
}

// Round 5
// 142.926 us; speedup vs baseline: 3.3819x; 1.0760x over previous
//
#include <hip/hip_runtime.h>

// MAB block: q=QWq^T+bq, k=(VWk^T+bk)*scale, v=VWv^T+bv, 8-head masked
// attention with residual (Oh = qh + A@vh), merge heads,
// out = O + relu(O Wo^T + bo).  B=4, N=2048, DIM=512, HEADS=8, d=64.
// All compute bf16-MFMA with f32 accumulation.

typedef __attribute__((ext_vector_type(8))) __bf16 bf16x8;
typedef __attribute__((ext_vector_type(4))) float f32x4;

#define DEV static __device__ __forceinline__

constexpr int DIMC = 512;
constexpr int NTOK = 2048;
constexpr int BB   = 4;
constexpr int MTOK = BB * NTOK;          // 8192
constexpr float SCALE2 = 0.04419417382415922f * 1.4426950408889634f; // /sqrt(512)*log2(e)

DEV unsigned short f2b(float f) {        // f32 -> bf16 bits, RNE (finite inputs)
  unsigned u = __float_as_uint(f);
  u = (u + 0x7FFFu + ((u >> 16) & 1u)) >> 16;
  return (unsigned short)u;
}
DEV float b2f(unsigned short b) { return __uint_as_float(((unsigned)b) << 16); }

DEV unsigned cvtpk(float a, float b) {   // {lo=bf16(a), hi=bf16(b)}
  unsigned r;
  asm("v_cvt_pk_bf16_f32 %0, %1, %2" : "=v"(r) : "v"(a), "v"(b));
  return r;
}

DEV bf16x8 pack8(unsigned d0, unsigned d1, unsigned d2, unsigned d3) {
  union { unsigned u[4]; bf16x8 v; } t;
  t.u[0] = d0; t.u[1] = d1; t.u[2] = d2; t.u[3] = d3;
  return t.v;
}

DEV void async_cp16(const void* src, void* dst) {
  __builtin_amdgcn_global_load_lds(
      (const __attribute__((address_space(1))) void*)(src),
      (__attribute__((address_space(3))) void*)(dst), 16, 0, 0);
}

// ------------- f32 -> bf16 conversion (4 weights) + mask detect -------------
__global__ void cvt_all(const float* __restrict__ Wq, const float* __restrict__ Wk,
                        const float* __restrict__ Wv, const float* __restrict__ Wo,
                        unsigned short* __restrict__ Wqb, unsigned short* __restrict__ Wkb,
                        unsigned short* __restrict__ Wvb, unsigned short* __restrict__ Wob,
                        const unsigned char* __restrict__ mask, int* __restrict__ flag) {
  if (blockIdx.x == 4096) {  // mask dtype detect: bool(1B) vs int/float(4B 0/1)
    int any = 0;
    for (int i = threadIdx.x; i < BB * NTOK; i += blockDim.x)
      if ((i & 3) == 1 && mask[i]) any = 1;
    if (any) atomicOr(flag, 1);
    return;
  }
  int i = blockIdx.x * blockDim.x + threadIdx.x;  // float4 index, 4 x 65536
  int wsel = i >> 16, off = i & 65535;
  const float* s = (wsel == 0) ? Wq : (wsel == 1) ? Wk : (wsel == 2) ? Wv : Wo;
  unsigned short* d = (wsel == 0) ? Wqb : (wsel == 1) ? Wkb : (wsel == 2) ? Wvb : Wob;
  float4 v = reinterpret_cast<const float4*>(s)[off];
  ushort4 o;
  o.x = f2b(v.x); o.y = f2b(v.y); o.z = f2b(v.z); o.w = f2b(v.w);
  reinterpret_cast<ushort4*>(d)[off] = o;
}

// ---------------- fused projection GEMM (LDS-staged, 128x128, BK=32) ----------------
// grid (4 colt, 64 rowt, 3 region): region 0=q, 1=k(scaled), 2=v(transposed to [d][tok]).
// A staged directly from f32 Q/V, converted in-register (cvt_pk). 4 waves (2x2),
// wave tile 64x64. Double-buffered LDS via global_load_lds w16, XOR-swizzled source.
__global__ __launch_bounds__(256) void proj_gemm(
    const float* __restrict__ Qf, const float* __restrict__ Vf,
    const unsigned short* __restrict__ Wqb, const unsigned short* __restrict__ Wkb,
    const unsigned short* __restrict__ Wvb,
    const float* __restrict__ bq, const float* __restrict__ bk,
    const float* __restrict__ bv,
    unsigned short* __restrict__ qbf, unsigned short* __restrict__ kbf,
    unsigned short* __restrict__ vtb) {
  __shared__ union {
    struct { float A[2][4096]; unsigned short B[2][4096]; } s;  // 32KB + 16KB
    unsigned short LT[128 * 136];                                // 34816B
  } lds;

  const int region = blockIdx.z;
  const float* Af = (region == 0) ? Qf : Vf;
  const unsigned short* W = (region == 0) ? Wqb : (region == 1) ? Wkb : Wvb;
  const float* bias = (region == 0) ? bq : (region == 1) ? bk : bv;

  const int tid = threadIdx.x;
  const int lane = tid & 63;
  const int w = tid >> 6;
  const int r = lane & 15, g = lane >> 4;
  const int rowB = blockIdx.y * 128;           // block row (token) base
  const int colB = blockIdx.x * 128;           // block col (dv) base
  const int rw = (w >> 1) * 64, cw = (w & 1) * 64;

  // stage 128 rows x 32 f32 of A (rows of 128B, slot^=row&7)
  auto stageA = [&](float* dst, int kk) {
#pragma unroll
    for (int i = 0; i < 4; ++i) {
      int off = i * 4096 + tid * 16;
      int row = off >> 7;
      int c = ((off >> 4) & 7) ^ (row & 7);
      async_cp16(Af + (size_t)(rowB + row) * DIMC + kk + c * 4, (char*)dst + off);
    }
  };
  // stage 128 rows x 32 bf16 of W (rows of 64B, slot^=row&3)
  auto stageB = [&](unsigned short* dst, int kk) {
#pragma unroll
    for (int i = 0; i < 2; ++i) {
      int off = i * 4096 + tid * 16;
      int row = off >> 6;
      int c = ((off >> 4) & 3) ^ (row & 3);
      async_cp16(W + (size_t)(colB + row) * DIMC + kk + c * 8, (char*)dst + off);
    }
  };

  f32x4 acc[4][4];
#pragma unroll
  for (int i = 0; i < 4; ++i)
#pragma unroll
    for (int j = 0; j < 4; ++j) acc[i][j] = f32x4{0.f, 0.f, 0.f, 0.f};

  stageA(lds.s.A[0], 0);
  stageB(lds.s.B[0], 0);
  __syncthreads();

  int cur = 0;
  for (int kk = 0; kk < DIMC; kk += 32) {
    if (kk + 32 < DIMC) {
      stageA(lds.s.A[cur ^ 1], kk + 32);
      stageB(lds.s.B[cur ^ 1], kk + 32);
    }
    const char* ap = (const char*)lds.s.A[cur];
    const char* bp = (const char*)lds.s.B[cur];
    bf16x8 af[4], bw[4];
#pragma unroll
    for (int i = 0; i < 4; ++i) {
      int row = rw + i * 16 + r;
      f32x4 lo = *reinterpret_cast<const f32x4*>(
          ap + row * 128 + (((2 * g) ^ (row & 7)) << 4));
      f32x4 hi = *reinterpret_cast<const f32x4*>(
          ap + row * 128 + (((2 * g + 1) ^ (row & 7)) << 4));
      af[i] = pack8(cvtpk(lo[0], lo[1]), cvtpk(lo[2], lo[3]),
                    cvtpk(hi[0], hi[1]), cvtpk(hi[2], hi[3]));
    }
#pragma unroll
    for (int j = 0; j < 4; ++j) {
      int row = cw + j * 16 + r;
      bw[j] = *reinterpret_cast<const bf16x8*>(bp + row * 64 + ((g ^ (row & 3)) * 16));
    }
    __builtin_amdgcn_s_setprio(1);
#pragma unroll
    for (int i = 0; i < 4; ++i)
#pragma unroll
      for (int j = 0; j < 4; ++j)
        acc[i][j] = __builtin_amdgcn_mfma_f32_16x16x32_bf16(af[i], bw[j],
                                                            acc[i][j], 0, 0, 0);
    __builtin_amdgcn_s_setprio(0);
    __syncthreads();
    cur ^= 1;
  }

  if (region != 2) {  // q / k: natural [tok][dv] bf16 store
    const float sc = (region == 1) ? SCALE2 : 1.0f;
    unsigned short* dst = (region == 1) ? kbf : qbf;
#pragma unroll
    for (int i = 0; i < 4; ++i)
#pragma unroll
      for (int j = 0; j < 4; ++j) {
        int n = colB + cw + j * 16 + r;
        float bn = bias[n];
#pragma unroll
        for (int q = 0; q < 4; ++q) {
          int m = rowB + rw + i * 16 + g * 4 + q;
          dst[(size_t)m * DIMC + n] = f2b((acc[i][j][q] + bn) * sc);
        }
      }
  } else {  // v: transpose 128x128 through LDS, store dense [d][tok] rows
#pragma unroll
    for (int i = 0; i < 4; ++i)
#pragma unroll
      for (int j = 0; j < 4; ++j) {
        int nl = cw + j * 16 + r;             // local dv 0..127
        float bn = bias[colB + nl];
        int tl = rw + i * 16 + g * 4;         // local token base (mult of 4)
        ushort4 o;
        o.x = f2b(acc[i][j][0] + bn);
        o.y = f2b(acc[i][j][1] + bn);
        o.z = f2b(acc[i][j][2] + bn);
        o.w = f2b(acc[i][j][3] + bn);
        *reinterpret_cast<ushort4*>(&lds.LT[nl * 136 + tl]) = o;
      }
    __syncthreads();
    int bidx = rowB >> 11, t0 = rowB & 2047;
#pragma unroll
    for (int rd = 0; rd < 8; ++rd) {
      int idx = rd * 256 + tid;               // 128 dv x 16 chunks
      int dv = idx >> 4, ch = idx & 15;
      int gdv = colB + dv, h = gdv >> 6, dd = gdv & 63;
      ushort4 v0 = *reinterpret_cast<const ushort4*>(&lds.LT[dv * 136 + ch * 8]);
      ushort4 v1 = *reinterpret_cast<const ushort4*>(&lds.LT[dv * 136 + ch * 8 + 4]);
      unsigned short* dst = vtb + (size_t)((bidx * 8 + h) * 64 + dd) * NTOK + t0 + ch * 8;
      reinterpret_cast<ushort4*>(dst)[0] = v0;
      reinterpret_cast<ushort4*>(dst)[1] = v1;
    }
  }
}

// ---------------- output GEMM: out = resid + relu(bf16(O) Wo^T + bo) ----------------
__global__ __launch_bounds__(256) void out_gemm(
    const float* __restrict__ Of32, const unsigned short* __restrict__ W,
    const float* __restrict__ bias, float* __restrict__ outf) {
  __shared__ struct { float A[2][2048]; unsigned short B[2][4096]; } lds;  // 32KB

  const int tid = threadIdx.x;
  const int lane = tid & 63;
  const int w = tid >> 6;
  const int r = lane & 15, g = lane >> 4;
  const int rowB = blockIdx.y * 64;
  const int colB = blockIdx.x * 128;
  const int rw = (w >> 1) * 32, cw = (w & 1) * 64;

  auto stageA = [&](float* dst, int kk) {  // 64 rows x 32 f32, 128B rows, c^=row&7
    int off = tid * 16;
#pragma unroll
    for (int i = 0; i < 2; ++i) {
      int o2 = off + i * 4096;
      int row = o2 >> 7;
      int c = ((o2 >> 4) & 7) ^ (row & 7);
      async_cp16(Of32 + (size_t)(rowB + row) * DIMC + kk + c * 4, (char*)dst + o2);
    }
  };
  auto stageB = [&](unsigned short* dst, int kk) {  // 128 x 32 bf16
#pragma unroll
    for (int i = 0; i < 2; ++i) {
      int off = i * 4096 + tid * 16;
      int row = off >> 6;
      int c = ((off >> 4) & 3) ^ (row & 3);
      async_cp16(W + (size_t)(colB + row) * DIMC + kk + c * 8, (char*)dst + off);
    }
  };

  f32x4 acc[2][4];
#pragma unroll
  for (int i = 0; i < 2; ++i)
#pragma unroll
    for (int j = 0; j < 4; ++j) acc[i][j] = f32x4{0.f, 0.f, 0.f, 0.f};

  stageA(lds.A[0], 0);
  stageB(lds.B[0], 0);
  __syncthreads();

  int cur = 0;
  for (int kk = 0; kk < DIMC; kk += 32) {
    if (kk + 32 < DIMC) {
      stageA(lds.A[cur ^ 1], kk + 32);
      stageB(lds.B[cur ^ 1], kk + 32);
    }
    const char* ap = (const char*)lds.A[cur];
    const char* bp = (const char*)lds.B[cur];
    bf16x8 af[2], bw[4];
#pragma unroll
    for (int i = 0; i < 2; ++i) {
      int row = rw + i * 16 + r;
      f32x4 lo = *reinterpret_cast<const f32x4*>(
          ap + row * 128 + (((2 * g) ^ (row & 7)) << 4));
      f32x4 hi = *reinterpret_cast<const f32x4*>(
          ap + row * 128 + (((2 * g + 1) ^ (row & 7)) << 4));
      af[i] = pack8(cvtpk(lo[0], lo[1]), cvtpk(lo[2], lo[3]),
                    cvtpk(hi[0], hi[1]), cvtpk(hi[2], hi[3]));
    }
#pragma unroll
    for (int j = 0; j < 4; ++j) {
      int row = cw + j * 16 + r;
      bw[j] = *reinterpret_cast<const bf16x8*>(bp + row * 64 + ((g ^ (row & 3)) * 16));
    }
    __builtin_amdgcn_s_setprio(1);
#pragma unroll
    for (int i = 0; i < 2; ++i)
#pragma unroll
      for (int j = 0; j < 4; ++j)
        acc[i][j] = __builtin_amdgcn_mfma_f32_16x16x32_bf16(af[i], bw[j],
                                                            acc[i][j], 0, 0, 0);
    __builtin_amdgcn_s_setprio(0);
    __syncthreads();
    cur ^= 1;
  }

#pragma unroll
  for (int i = 0; i < 2; ++i)
#pragma unroll
    for (int j = 0; j < 4; ++j) {
      int n = colB + cw + j * 16 + r;
      float bn = bias[n];
#pragma unroll
      for (int q = 0; q < 4; ++q) {
        int m = rowB + rw + i * 16 + g * 4 + q;
        float val = acc[i][j][q] + bn;
        outf[(size_t)m * DIMC + n] = Of32[(size_t)m * DIMC + n] + fmaxf(val, 0.f);
      }
    }
}

// ---------------- fused masked attention with residual ----------------
// grid (N/128, B*H), 8 waves/block, wave owns 16 q-rows, 128-key tiles
// double-buffered in LDS. K rows staged sigma-PERMUTED so the swapped-QK^T
// D-layout per lane IS the PV A-fragment order (P stays in registers).
// Mask folded into the QK MFMA C-initializer: s[f] starts at MaskAdd[tok]
// (0 or -16384), so masked logits underflow to exactly 0 in exp2 -- zero
// per-element mask VALU. k pre-scaled by SCALE2 (exp2 domain).
__global__ __launch_bounds__(512, 4) void attn_kernel(
    const unsigned short* __restrict__ qb, const unsigned short* __restrict__ kb,
    const unsigned short* __restrict__ vt, const unsigned char* __restrict__ mask8,
    const int* __restrict__ flagp, float* __restrict__ Of32) {
  __shared__ unsigned short Kt[2][128 * 64];  // 16KB each: [key][d], 128B rows
  __shared__ unsigned short Vt[2][64 * 128];  // 16KB each: [d][key], 256B rows
  __shared__ float MaskAdd[NTOK];             // 8KB: 0 or -16384

  const int tid = threadIdx.x;
  const int lane = tid & 63;
  const int w = tid >> 6;                     // 0..7
  const int r = lane & 15, g = lane >> 4;
  const int bh = blockIdx.y, b = bh >> 3, h = bh & 7;
  const int q0 = blockIdx.x * 128 + w * 16;
  const size_t rowbase = (size_t)b * NTOK;
  const int flag = *flagp;
  const unsigned* mask32 = (const unsigned*)mask8;

  for (int i = tid; i < NTOK; i += 512) {
    unsigned v = flag ? (unsigned)mask8[b * NTOK + i] : mask32[b * NTOK + i];
    MaskAdd[i] = v ? 0.f : -16384.f;
  }

  // Q fragments (B-operand): col=q-row at lane r, k(d)-chunk g*8
  bf16x8 aq[2];
#pragma unroll
  for (int ks = 0; ks < 2; ++ks)
    aq[ks] = *reinterpret_cast<const bf16x8*>(
        qb + (rowbase + q0 + r) * DIMC + h * 64 + ks * 32 + g * 8);

  const unsigned short* kgb = kb + rowbase * DIMC + h * 64;  // + key*512
  const unsigned short* vgb = vt + (size_t)bh * 64 * NTOK;   // + d*2048 + key

  auto stageK = [&](int buf, int kt) {
#pragma unroll
    for (int i = 0; i < 2; ++i) {
      int off = i * 8192 + tid * 16;                // byte offset in 16KB tile
      int row = off >> 7;                           // tile row 0..127
      int s16 = ((off >> 4) & 7) ^ (row & 7);       // swizzled 16B slot
      int half = row >> 6, rr = row & 63;
      int ff = rr >> 4, gg = (rr >> 2) & 3, j = rr & 3;
      int tok = half * 64 + 8 * gg + 4 * (ff & 1) + 32 * (ff >> 1) + j;  // sigma
      async_cp16(kgb + (size_t)(kt + tok) * DIMC + (s16 << 3),
                 (char*)&Kt[buf][0] + off);
    }
  };
  auto stageV = [&](int buf, int kt) {
#pragma unroll
    for (int i = 0; i < 2; ++i) {
      int off = i * 8192 + tid * 16;
      int row = off >> 8;                           // d 0..63, keys natural
      int s16 = ((off >> 4) & 15) ^ (row & 15);
      async_cp16(vgb + (size_t)row * NTOK + kt + (s16 << 3),
                 (char*)&Vt[buf][0] + off);
    }
  };

  stageK(0, 0);
  stageV(0, 0);
  __syncthreads();

  float mrun = -1e30f, lrun = 0.f;
  f32x4 oacc[4];
#pragma unroll
  for (int f = 0; f < 4; ++f) oacc[f] = f32x4{0.f, 0.f, 0.f, 0.f};

  const int kswz = (r & 7) << 4;
  const int vswz = r << 4;
  int cur = 0;
  for (int kt = 0; kt < NTOK; kt += 128) {
    if (kt + 128 < NTOK) {
      stageK(cur ^ 1, kt + 128);
      stageV(cur ^ 1, kt + 128);
    }

    // QK^T (swapped), C initialized with the mask addend
    f32x4 s[8];
#pragma unroll
    for (int f = 0; f < 8; ++f) {
      int tb = kt + ((f >> 2) << 6) + 8 * g + 4 * (f & 1) + 32 * ((f >> 1) & 1);
      s[f] = *reinterpret_cast<const f32x4*>(&MaskAdd[tb]);
    }
    const unsigned char* kp = (const unsigned char*)&Kt[cur][0];
    __builtin_amdgcn_s_setprio(1);
#pragma unroll
    for (int ks = 0; ks < 2; ++ks)
#pragma unroll
      for (int f = 0; f < 8; ++f) {
        bf16x8 kf = *reinterpret_cast<const bf16x8*>(
            kp + (f * 16 + r) * 128 + ((ks * 64 + g * 16) ^ kswz));
        s[f] = __builtin_amdgcn_mfma_f32_16x16x32_bf16(kf, aq[ks], s[f], 0, 0, 0);
      }
    __builtin_amdgcn_s_setprio(0);

    // row max, tree (max3-fusable); lane owns 32 keys of q-row r
    float ma[8];
#pragma unroll
    for (int f = 0; f < 8; ++f)
      ma[f] = fmaxf(fmaxf(s[f][0], s[f][1]), fmaxf(s[f][2], s[f][3]));
    float tm = fmaxf(fmaxf(fmaxf(ma[0], ma[1]), fmaxf(ma[2], ma[3])),
                     fmaxf(fmaxf(ma[4], ma[5]), fmaxf(ma[6], ma[7])));
    tm = fmaxf(tm, __shfl_xor(tm, 16));
    tm = fmaxf(tm, __shfl_xor(tm, 32));
    if (!__all(tm <= mrun + 8.f)) {       // defer-max: rescale only when needed
      float mnew = fmaxf(mrun, tm);
      float corr = __builtin_exp2f(mrun - mnew);
      lrun *= corr;
      mrun = mnew;
#pragma unroll
      for (int j = 0; j < 4; ++j) {
        float cj = __shfl(corr, (lane & 48) | (g * 4 + j));
#pragma unroll
        for (int f = 0; f < 4; ++f) oacc[f][j] *= cj;
      }
    }
#pragma unroll
    for (int f = 0; f < 8; ++f)
#pragma unroll
      for (int j = 0; j < 4; ++j) s[f][j] = __builtin_exp2f(s[f][j] - mrun);
    float sf[8];
#pragma unroll
    for (int f = 0; f < 8; ++f)
      sf[f] = (s[f][0] + s[f][1]) + (s[f][2] + s[f][3]);
    float rs = ((sf[0] + sf[1]) + (sf[2] + sf[3])) +
               ((sf[4] + sf[5]) + (sf[6] + sf[7]));
    rs += __shfl_xor(rs, 16);
    rs += __shfl_xor(rs, 32);
    lrun += rs;

    // P -> PV A-fragments, fully in-register (sigma makes the order line up)
    bf16x8 pa[4];
#pragma unroll
    for (int ks = 0; ks < 4; ++ks) {
      int F0 = 4 * (ks >> 1) + 2 * (ks & 1);
      pa[ks] = pack8(cvtpk(s[F0][0], s[F0][1]), cvtpk(s[F0][2], s[F0][3]),
                     cvtpk(s[F0 + 1][0], s[F0 + 1][1]),
                     cvtpk(s[F0 + 1][2], s[F0 + 1][3]));
    }

    // PV: oacc[f] (cols d=f*16+r, rows q=g*4+j) += P @ V
    const unsigned char* vp = (const unsigned char*)&Vt[cur][0];
    __builtin_amdgcn_s_setprio(1);
#pragma unroll
    for (int ks = 0; ks < 4; ++ks)
#pragma unroll
      for (int f = 0; f < 4; ++f) {
        bf16x8 vf = *reinterpret_cast<const bf16x8*>(
            vp + (f * 16 + r) * 256 + ((ks * 64 + g * 16) ^ vswz));
        oacc[f] = __builtin_amdgcn_mfma_f32_16x16x32_bf16(pa[ks], vf, oacc[f], 0, 0, 0);
      }
    __builtin_amdgcn_s_setprio(0);

    __syncthreads();  // drains prefetch vmcnt; all waves done with buf cur
    cur ^= 1;
  }

  // epilogue: O = q + PV/l  (oacc row = q-row g*4+j, col = d f*16+r)
#pragma unroll
  for (int j = 0; j < 4; ++j) {
    float linv = 1.0f / __shfl(lrun, (lane & 48) | (g * 4 + j));
    int row = q0 + g * 4 + j;
#pragma unroll
    for (int f = 0; f < 4; ++f) {
      int col = h * 64 + f * 16 + r;
      size_t idx = (rowbase + row) * DIMC + col;
      Of32[idx] = b2f(qb[idx]) + oacc[f][j] * linv;
    }
  }
}

extern "C" void kernel_launch(void* const* d_in, const int* in_sizes, int n_in,
                              void* d_out, int out_size, void* d_ws, size_t ws_size,
                              hipStream_t stream) {
  const float* Q  = (const float*)d_in[0];
  const float* V  = (const float*)d_in[1];
  const unsigned char* mask = (const unsigned char*)d_in[2];
  const float* Wq = (const float*)d_in[3];
  const float* bq = (const float*)d_in[4];
  const float* Wk = (const float*)d_in[5];
  const float* bk = (const float*)d_in[6];
  const float* Wv = (const float*)d_in[7];
  const float* bv = (const float*)d_in[8];
  const float* Wo = (const float*)d_in[9];
  const float* bo = (const float*)d_in[10];

  char* ws = (char*)d_ws;
  size_t off = 0;
  auto alloc = [&](size_t bytes) -> void* {
    void* p = ws + off;
    off += (bytes + 255) & ~(size_t)255;
    return p;
  };
  int* flag = (int*)alloc(4);
  unsigned short* Wqb = (unsigned short*)alloc((size_t)DIMC * DIMC * 2);
  unsigned short* Wkb = (unsigned short*)alloc((size_t)DIMC * DIMC * 2);
  unsigned short* Wvb = (unsigned short*)alloc((size_t)DIMC * DIMC * 2);
  unsigned short* Wob = (unsigned short*)alloc((size_t)DIMC * DIMC * 2);
  unsigned short* qbf = (unsigned short*)alloc((size_t)MTOK * DIMC * 2);
  unsigned short* kbf = (unsigned short*)alloc((size_t)MTOK * DIMC * 2);
  unsigned short* vtb = (unsigned short*)alloc((size_t)MTOK * DIMC * 2);
  float* Of32 = (float*)alloc((size_t)MTOK * DIMC * 4);

  hipMemsetAsync(flag, 0, 4, stream);

  cvt_all<<<4097, 256, 0, stream>>>(Wq, Wk, Wv, Wo, Wqb, Wkb, Wvb, Wob,
                                    mask, flag);

  proj_gemm<<<dim3(4, MTOK / 128, 3), 256, 0, stream>>>(
      Q, V, Wqb, Wkb, Wvb, bq, bk, bv, qbf, kbf, vtb);

  attn_kernel<<<dim3(NTOK / 128, BB * 8), 512, 0, stream>>>(
      qbf, kbf, vtb, mask, flag, Of32);

  out_gemm<<<dim3(4, MTOK / 64), 256, 0, stream>>>(
      Of32, Wob, bo, (float*)d_out);
}

// Round 6
// 129.554 us; speedup vs baseline: 3.7310x; 1.1032x over previous
//
#include <hip/hip_runtime.h>

// MAB block: q=QWq^T+bq, k=(VWk^T+bk)*scale, v=VWv^T+bv, 8-head masked
// attention with residual (Oh = qh + A@vh), merge heads,
// out = O + relu(O Wo^T + bo).  B=4, N=2048, DIM=512, HEADS=8, d=64.
// All compute bf16-MFMA with f32 accumulation.

typedef __attribute__((ext_vector_type(8))) __bf16 bf16x8;
typedef __attribute__((ext_vector_type(4))) float f32x4;

#define DEV static __device__ __forceinline__

constexpr int DIMC = 512;
constexpr int NTOK = 2048;
constexpr int BB   = 4;
constexpr int MTOK = BB * NTOK;          // 8192
constexpr float SCALE2 = 0.04419417382415922f * 1.4426950408889634f; // /sqrt(512)*log2(e)

DEV unsigned short f2b(float f) {        // f32 -> bf16 bits, RNE (finite inputs)
  unsigned u = __float_as_uint(f);
  u = (u + 0x7FFFu + ((u >> 16) & 1u)) >> 16;
  return (unsigned short)u;
}
DEV float b2f(unsigned short b) { return __uint_as_float(((unsigned)b) << 16); }

DEV unsigned cvtpk(float a, float b) {   // {lo=bf16(a), hi=bf16(b)}
  unsigned r;
  asm("v_cvt_pk_bf16_f32 %0, %1, %2" : "=v"(r) : "v"(a), "v"(b));
  return r;
}

DEV bf16x8 pack8(unsigned d0, unsigned d1, unsigned d2, unsigned d3) {
  union { unsigned u[4]; bf16x8 v; } t;
  t.u[0] = d0; t.u[1] = d1; t.u[2] = d2; t.u[3] = d3;
  return t.v;
}

DEV void async_cp16(const void* src, void* dst) {
  __builtin_amdgcn_global_load_lds(
      (const __attribute__((address_space(1))) void*)(src),
      (__attribute__((address_space(3))) void*)(dst), 16, 0, 0);
}

// ------------- f32 -> bf16 conversion (4 weights) + mask detect -------------
__global__ void cvt_all(const float* __restrict__ Wq, const float* __restrict__ Wk,
                        const float* __restrict__ Wv, const float* __restrict__ Wo,
                        unsigned short* __restrict__ Wqb, unsigned short* __restrict__ Wkb,
                        unsigned short* __restrict__ Wvb, unsigned short* __restrict__ Wob,
                        const unsigned char* __restrict__ mask, int* __restrict__ flag) {
  if (blockIdx.x == 4096) {  // mask dtype detect: bool(1B) vs int/float(4B 0/1)
    int any = 0;
    for (int i = threadIdx.x; i < BB * NTOK; i += blockDim.x)
      if ((i & 3) == 1 && mask[i]) any = 1;
    if (any) atomicOr(flag, 1);
    return;
  }
  int i = blockIdx.x * blockDim.x + threadIdx.x;  // float4 index, 4 x 65536
  int wsel = i >> 16, off = i & 65535;
  const float* s = (wsel == 0) ? Wq : (wsel == 1) ? Wk : (wsel == 2) ? Wv : Wo;
  unsigned short* d = (wsel == 0) ? Wqb : (wsel == 1) ? Wkb : (wsel == 2) ? Wvb : Wob;
  float4 v = reinterpret_cast<const float4*>(s)[off];
  ushort4 o;
  o.x = f2b(v.x); o.y = f2b(v.y); o.z = f2b(v.z); o.w = f2b(v.w);
  reinterpret_cast<ushort4*>(d)[off] = o;
}

// ---------------- fused projection GEMM (LDS-staged, 128x128, BK=32) ----------------
// grid (64 rowt, 4 colt, 3 region): x-major = rowt so colt-siblings (stride 64)
// and regions (stride 256) land on the SAME XCD -> A panel is L2-shared.
// region 0=q, 1=k(scaled), 2=v(transposed to [d][tok]). A staged from f32 Q/V,
// converted in-register (cvt_pk). 4 waves (2x2), wave tile 64x64.
__global__ __launch_bounds__(256) void proj_gemm(
    const float* __restrict__ Qf, const float* __restrict__ Vf,
    const unsigned short* __restrict__ Wqb, const unsigned short* __restrict__ Wkb,
    const unsigned short* __restrict__ Wvb,
    const float* __restrict__ bq, const float* __restrict__ bk,
    const float* __restrict__ bv,
    unsigned short* __restrict__ qbf, unsigned short* __restrict__ kbf,
    unsigned short* __restrict__ vtb) {
  __shared__ union {
    struct { float A[2][4096]; unsigned short B[2][4096]; } s;  // 32KB + 16KB
    unsigned short LT[128 * 136];                                // 34816B
  } lds;

  const int region = blockIdx.z;
  const float* Af = (region == 0) ? Qf : Vf;
  const unsigned short* W = (region == 0) ? Wqb : (region == 1) ? Wkb : Wvb;
  const float* bias = (region == 0) ? bq : (region == 1) ? bk : bv;

  const int tid = threadIdx.x;
  const int lane = tid & 63;
  const int w = tid >> 6;
  const int r = lane & 15, g = lane >> 4;
  const int rowB = blockIdx.x * 128;           // block row (token) base
  const int colB = blockIdx.y * 128;           // block col (dv) base
  const int rw = (w >> 1) * 64, cw = (w & 1) * 64;

  // stage 128 rows x 32 f32 of A (rows of 128B, slot^=row&7)
  auto stageA = [&](float* dst, int kk) {
#pragma unroll
    for (int i = 0; i < 4; ++i) {
      int off = i * 4096 + tid * 16;
      int row = off >> 7;
      int c = ((off >> 4) & 7) ^ (row & 7);
      async_cp16(Af + (size_t)(rowB + row) * DIMC + kk + c * 4, (char*)dst + off);
    }
  };
  // stage 128 rows x 32 bf16 of W (rows of 64B, slot^=row&3)
  auto stageB = [&](unsigned short* dst, int kk) {
#pragma unroll
    for (int i = 0; i < 2; ++i) {
      int off = i * 4096 + tid * 16;
      int row = off >> 6;
      int c = ((off >> 4) & 3) ^ (row & 3);
      async_cp16(W + (size_t)(colB + row) * DIMC + kk + c * 8, (char*)dst + off);
    }
  };

  f32x4 acc[4][4];
#pragma unroll
  for (int i = 0; i < 4; ++i)
#pragma unroll
    for (int j = 0; j < 4; ++j) acc[i][j] = f32x4{0.f, 0.f, 0.f, 0.f};

  stageA(lds.s.A[0], 0);
  stageB(lds.s.B[0], 0);
  __syncthreads();

  int cur = 0;
  for (int kk = 0; kk < DIMC; kk += 32) {
    if (kk + 32 < DIMC) {
      stageA(lds.s.A[cur ^ 1], kk + 32);
      stageB(lds.s.B[cur ^ 1], kk + 32);
    }
    const char* ap = (const char*)lds.s.A[cur];
    const char* bp = (const char*)lds.s.B[cur];
    bf16x8 af[4], bw[4];
#pragma unroll
    for (int i = 0; i < 4; ++i) {
      int row = rw + i * 16 + r;
      f32x4 lo = *reinterpret_cast<const f32x4*>(
          ap + row * 128 + (((2 * g) ^ (row & 7)) << 4));
      f32x4 hi = *reinterpret_cast<const f32x4*>(
          ap + row * 128 + (((2 * g + 1) ^ (row & 7)) << 4));
      af[i] = pack8(cvtpk(lo[0], lo[1]), cvtpk(lo[2], lo[3]),
                    cvtpk(hi[0], hi[1]), cvtpk(hi[2], hi[3]));
    }
#pragma unroll
    for (int j = 0; j < 4; ++j) {
      int row = cw + j * 16 + r;
      bw[j] = *reinterpret_cast<const bf16x8*>(bp + row * 64 + ((g ^ (row & 3)) * 16));
    }
    __builtin_amdgcn_s_setprio(1);
#pragma unroll
    for (int i = 0; i < 4; ++i)
#pragma unroll
      for (int j = 0; j < 4; ++j)
        acc[i][j] = __builtin_amdgcn_mfma_f32_16x16x32_bf16(af[i], bw[j],
                                                            acc[i][j], 0, 0, 0);
    __builtin_amdgcn_s_setprio(0);
    __syncthreads();
    cur ^= 1;
  }

  if (region != 2) {  // q / k: natural [tok][dv] bf16 store
    const float sc = (region == 1) ? SCALE2 : 1.0f;
    unsigned short* dst = (region == 1) ? kbf : qbf;
#pragma unroll
    for (int i = 0; i < 4; ++i)
#pragma unroll
      for (int j = 0; j < 4; ++j) {
        int n = colB + cw + j * 16 + r;
        float bn = bias[n];
#pragma unroll
        for (int q = 0; q < 4; ++q) {
          int m = rowB + rw + i * 16 + g * 4 + q;
          dst[(size_t)m * DIMC + n] = f2b((acc[i][j][q] + bn) * sc);
        }
      }
  } else {  // v: transpose 128x128 through LDS, store dense [d][tok] rows
#pragma unroll
    for (int i = 0; i < 4; ++i)
#pragma unroll
      for (int j = 0; j < 4; ++j) {
        int nl = cw + j * 16 + r;             // local dv 0..127
        float bn = bias[colB + nl];
        int tl = rw + i * 16 + g * 4;         // local token base (mult of 4)
        ushort4 o;
        o.x = f2b(acc[i][j][0] + bn);
        o.y = f2b(acc[i][j][1] + bn);
        o.z = f2b(acc[i][j][2] + bn);
        o.w = f2b(acc[i][j][3] + bn);
        *reinterpret_cast<ushort4*>(&lds.LT[nl * 136 + tl]) = o;
      }
    __syncthreads();
    int bidx = rowB >> 11, t0 = rowB & 2047;
#pragma unroll
    for (int rd = 0; rd < 8; ++rd) {
      int idx = rd * 256 + tid;               // 128 dv x 16 chunks
      int dv = idx >> 4, ch = idx & 15;
      int gdv = colB + dv, h = gdv >> 6, dd = gdv & 63;
      ushort4 v0 = *reinterpret_cast<const ushort4*>(&lds.LT[dv * 136 + ch * 8]);
      ushort4 v1 = *reinterpret_cast<const ushort4*>(&lds.LT[dv * 136 + ch * 8 + 4]);
      unsigned short* dst = vtb + (size_t)((bidx * 8 + h) * 64 + dd) * NTOK + t0 + ch * 8;
      reinterpret_cast<ushort4*>(dst)[0] = v0;
      reinterpret_cast<ushort4*>(dst)[1] = v1;
    }
  }
}

// ---------------- output GEMM: out = resid + relu(bf16(O) Wo^T + bo) ----------------
// grid (128 rowt, 4 colt): colt-siblings at stride 128 -> same XCD (A L2-shared).
__global__ __launch_bounds__(256) void out_gemm(
    const float* __restrict__ Of32, const unsigned short* __restrict__ W,
    const float* __restrict__ bias, float* __restrict__ outf) {
  __shared__ struct { float A[2][2048]; unsigned short B[2][4096]; } lds;  // 32KB

  const int tid = threadIdx.x;
  const int lane = tid & 63;
  const int w = tid >> 6;
  const int r = lane & 15, g = lane >> 4;
  const int rowB = blockIdx.x * 64;
  const int colB = blockIdx.y * 128;
  const int rw = (w >> 1) * 32, cw = (w & 1) * 64;

  auto stageA = [&](float* dst, int kk) {  // 64 rows x 32 f32, 128B rows, c^=row&7
    int off = tid * 16;
#pragma unroll
    for (int i = 0; i < 2; ++i) {
      int o2 = off + i * 4096;
      int row = o2 >> 7;
      int c = ((o2 >> 4) & 7) ^ (row & 7);
      async_cp16(Of32 + (size_t)(rowB + row) * DIMC + kk + c * 4, (char*)dst + o2);
    }
  };
  auto stageB = [&](unsigned short* dst, int kk) {  // 128 x 32 bf16
#pragma unroll
    for (int i = 0; i < 2; ++i) {
      int off = i * 4096 + tid * 16;
      int row = off >> 6;
      int c = ((off >> 4) & 3) ^ (row & 3);
      async_cp16(W + (size_t)(colB + row) * DIMC + kk + c * 8, (char*)dst + off);
    }
  };

  f32x4 acc[2][4];
#pragma unroll
  for (int i = 0; i < 2; ++i)
#pragma unroll
    for (int j = 0; j < 4; ++j) acc[i][j] = f32x4{0.f, 0.f, 0.f, 0.f};

  stageA(lds.A[0], 0);
  stageB(lds.B[0], 0);
  __syncthreads();

  int cur = 0;
  for (int kk = 0; kk < DIMC; kk += 32) {
    if (kk + 32 < DIMC) {
      stageA(lds.A[cur ^ 1], kk + 32);
      stageB(lds.B[cur ^ 1], kk + 32);
    }
    const char* ap = (const char*)lds.A[cur];
    const char* bp = (const char*)lds.B[cur];
    bf16x8 af[2], bw[4];
#pragma unroll
    for (int i = 0; i < 2; ++i) {
      int row = rw + i * 16 + r;
      f32x4 lo = *reinterpret_cast<const f32x4*>(
          ap + row * 128 + (((2 * g) ^ (row & 7)) << 4));
      f32x4 hi = *reinterpret_cast<const f32x4*>(
          ap + row * 128 + (((2 * g + 1) ^ (row & 7)) << 4));
      af[i] = pack8(cvtpk(lo[0], lo[1]), cvtpk(lo[2], lo[3]),
                    cvtpk(hi[0], hi[1]), cvtpk(hi[2], hi[3]));
    }
#pragma unroll
    for (int j = 0; j < 4; ++j) {
      int row = cw + j * 16 + r;
      bw[j] = *reinterpret_cast<const bf16x8*>(bp + row * 64 + ((g ^ (row & 3)) * 16));
    }
    __builtin_amdgcn_s_setprio(1);
#pragma unroll
    for (int i = 0; i < 2; ++i)
#pragma unroll
      for (int j = 0; j < 4; ++j)
        acc[i][j] = __builtin_amdgcn_mfma_f32_16x16x32_bf16(af[i], bw[j],
                                                            acc[i][j], 0, 0, 0);
    __builtin_amdgcn_s_setprio(0);
    __syncthreads();
    cur ^= 1;
  }

#pragma unroll
  for (int i = 0; i < 2; ++i)
#pragma unroll
    for (int j = 0; j < 4; ++j) {
      int n = colB + cw + j * 16 + r;
      float bn = bias[n];
#pragma unroll
      for (int q = 0; q < 4; ++q) {
        int m = rowB + rw + i * 16 + g * 4 + q;
        float val = acc[i][j][q] + bn;
        outf[(size_t)m * DIMC + n] = Of32[(size_t)m * DIMC + n] + fmaxf(val, 0.f);
      }
    }
}

// ---------------- fused masked attention with residual ----------------
// grid (32 bh, 16 qt): same-bh q-tiles at stride 32 -> same XCD (K/V L2-shared).
// 4 waves/block, wave owns 32 q-rows (two 16-q B-operands) so every K/V LDS
// fragment read feeds TWO MFMAs (halves LDS traffic per MFMA). 128-key tiles
// double-buffered. K rows staged sigma-PERMUTED so the swapped-QK^T D-layout
// per lane IS the PV A-fragment order (P stays in registers). Mask folded into
// the QK MFMA C-initializer (0 or -16384 -> exp2 underflows to exact 0).
__global__ __launch_bounds__(256, 2) void attn_kernel(
    const unsigned short* __restrict__ qb, const unsigned short* __restrict__ kb,
    const unsigned short* __restrict__ vt, const unsigned char* __restrict__ mask8,
    const int* __restrict__ flagp, float* __restrict__ Of32) {
  __shared__ unsigned short Kt[2][128 * 64];  // 16KB each: [key][d], 128B rows
  __shared__ unsigned short Vt[2][64 * 128];  // 16KB each: [d][key], 256B rows
  __shared__ float MaskAdd[NTOK];             // 8KB: 0 or -16384

  const int tid = threadIdx.x;
  const int lane = tid & 63;
  const int w = tid >> 6;                     // 0..3
  const int r = lane & 15, g = lane >> 4;
  const int bh = blockIdx.x, b = bh >> 3, h = bh & 7;
  const int q0 = blockIdx.y * 128 + w * 32;
  const size_t rowbase = (size_t)b * NTOK;
  const int flag = *flagp;
  const unsigned* mask32 = (const unsigned*)mask8;

  for (int i = tid; i < NTOK; i += 256) {
    unsigned v = flag ? (unsigned)mask8[b * NTOK + i] : mask32[b * NTOK + i];
    MaskAdd[i] = v ? 0.f : -16384.f;
  }

  // Q fragments (B-operand): col=q-row at lane r, k(d)-chunk g*8; two q-subtiles
  bf16x8 aq0[2], aq1[2];
#pragma unroll
  for (int ks = 0; ks < 2; ++ks) {
    aq0[ks] = *reinterpret_cast<const bf16x8*>(
        qb + (rowbase + q0 + r) * DIMC + h * 64 + ks * 32 + g * 8);
    aq1[ks] = *reinterpret_cast<const bf16x8*>(
        qb + (rowbase + q0 + 16 + r) * DIMC + h * 64 + ks * 32 + g * 8);
  }

  const unsigned short* kgb = kb + rowbase * DIMC + h * 64;  // + key*512
  const unsigned short* vgb = vt + (size_t)bh * 64 * NTOK;   // + d*2048 + key

  auto stageK = [&](int buf, int kt) {
#pragma unroll
    for (int i = 0; i < 4; ++i) {
      int off = i * 4096 + tid * 16;                // byte offset in 16KB tile
      int row = off >> 7;                           // tile row 0..127
      int s16 = ((off >> 4) & 7) ^ (row & 7);       // swizzled 16B slot
      int half = row >> 6, rr = row & 63;
      int ff = rr >> 4, gg = (rr >> 2) & 3, j = rr & 3;
      int tok = half * 64 + 8 * gg + 4 * (ff & 1) + 32 * (ff >> 1) + j;  // sigma
      async_cp16(kgb + (size_t)(kt + tok) * DIMC + (s16 << 3),
                 (char*)&Kt[buf][0] + off);
    }
  };
  auto stageV = [&](int buf, int kt) {
#pragma unroll
    for (int i = 0; i < 4; ++i) {
      int off = i * 4096 + tid * 16;
      int row = off >> 8;                           // d 0..63, keys natural
      int s16 = ((off >> 4) & 15) ^ (row & 15);
      async_cp16(vgb + (size_t)row * NTOK + kt + (s16 << 3),
                 (char*)&Vt[buf][0] + off);
    }
  };

  stageK(0, 0);
  stageV(0, 0);
  __syncthreads();

  float mrun0 = -1e30f, lrun0 = 0.f, mrun1 = -1e30f, lrun1 = 0.f;
  f32x4 oacc0[4], oacc1[4];
#pragma unroll
  for (int f = 0; f < 4; ++f) {
    oacc0[f] = f32x4{0.f, 0.f, 0.f, 0.f};
    oacc1[f] = f32x4{0.f, 0.f, 0.f, 0.f};
  }

  const int kswz = (r & 7) << 4;
  const int vswz = r << 4;

  // online softmax + P->bf16 A-fragments for one 16-q subtile
  auto softmax_pa = [&](f32x4 (&s)[8], float& mr, float& lr, f32x4 (&oa)[4],
                        bf16x8 (&pa)[4]) {
    float ma[8];
#pragma unroll
    for (int f = 0; f < 8; ++f)
      ma[f] = fmaxf(fmaxf(s[f][0], s[f][1]), fmaxf(s[f][2], s[f][3]));
    float tm = fmaxf(fmaxf(fmaxf(ma[0], ma[1]), fmaxf(ma[2], ma[3])),
                     fmaxf(fmaxf(ma[4], ma[5]), fmaxf(ma[6], ma[7])));
    tm = fmaxf(tm, __shfl_xor(tm, 16));
    tm = fmaxf(tm, __shfl_xor(tm, 32));
    if (!__all(tm <= mr + 8.f)) {       // defer-max: rescale only when needed
      float mnew = fmaxf(mr, tm);
      float corr = __builtin_exp2f(mr - mnew);
      lr *= corr;
      mr = mnew;
#pragma unroll
      for (int j = 0; j < 4; ++j) {
        float cj = __shfl(corr, (lane & 48) | (g * 4 + j));
#pragma unroll
        for (int f = 0; f < 4; ++f) oa[f][j] *= cj;
      }
    }
#pragma unroll
    for (int f = 0; f < 8; ++f)
#pragma unroll
      for (int j = 0; j < 4; ++j) s[f][j] = __builtin_exp2f(s[f][j] - mr);
    float sf[8];
#pragma unroll
    for (int f = 0; f < 8; ++f)
      sf[f] = (s[f][0] + s[f][1]) + (s[f][2] + s[f][3]);
    float rs = ((sf[0] + sf[1]) + (sf[2] + sf[3])) +
               ((sf[4] + sf[5]) + (sf[6] + sf[7]));
    rs += __shfl_xor(rs, 16);
    rs += __shfl_xor(rs, 32);
    lr += rs;
#pragma unroll
    for (int ks = 0; ks < 4; ++ks) {
      int F0 = 4 * (ks >> 1) + 2 * (ks & 1);
      pa[ks] = pack8(cvtpk(s[F0][0], s[F0][1]), cvtpk(s[F0][2], s[F0][3]),
                     cvtpk(s[F0 + 1][0], s[F0 + 1][1]),
                     cvtpk(s[F0 + 1][2], s[F0 + 1][3]));
    }
  };

  int cur = 0;
  for (int kt = 0; kt < NTOK; kt += 128) {
    if (kt + 128 < NTOK) {
      stageK(cur ^ 1, kt + 128);
      stageV(cur ^ 1, kt + 128);
    }

    // QK^T (swapped), C initialized with the mask addend; each kf feeds 2 MFMAs
    f32x4 s0[8], s1[8];
#pragma unroll
    for (int f = 0; f < 8; ++f) {
      int tb = kt + ((f >> 2) << 6) + 8 * g + 4 * (f & 1) + 32 * ((f >> 1) & 1);
      f32x4 mc = *reinterpret_cast<const f32x4*>(&MaskAdd[tb]);
      s0[f] = mc;
      s1[f] = mc;
    }
    const unsigned char* kp = (const unsigned char*)&Kt[cur][0];
    __builtin_amdgcn_s_setprio(1);
#pragma unroll
    for (int ks = 0; ks < 2; ++ks)
#pragma unroll
      for (int f = 0; f < 8; ++f) {
        bf16x8 kf = *reinterpret_cast<const bf16x8*>(
            kp + (f * 16 + r) * 128 + ((ks * 64 + g * 16) ^ kswz));
        s0[f] = __builtin_amdgcn_mfma_f32_16x16x32_bf16(kf, aq0[ks], s0[f], 0, 0, 0);
        s1[f] = __builtin_amdgcn_mfma_f32_16x16x32_bf16(kf, aq1[ks], s1[f], 0, 0, 0);
      }
    __builtin_amdgcn_s_setprio(0);

    bf16x8 pa0[4], pa1[4];
    softmax_pa(s0, mrun0, lrun0, oacc0, pa0);
    softmax_pa(s1, mrun1, lrun1, oacc1, pa1);

    // PV: each vf feeds 2 MFMAs (both q-subtiles)
    const unsigned char* vp = (const unsigned char*)&Vt[cur][0];
    __builtin_amdgcn_s_setprio(1);
#pragma unroll
    for (int ks = 0; ks < 4; ++ks)
#pragma unroll
      for (int f = 0; f < 4; ++f) {
        bf16x8 vf = *reinterpret_cast<const bf16x8*>(
            vp + (f * 16 + r) * 256 + ((ks * 64 + g * 16) ^ vswz));
        oacc0[f] = __builtin_amdgcn_mfma_f32_16x16x32_bf16(pa0[ks], vf, oacc0[f], 0, 0, 0);
        oacc1[f] = __builtin_amdgcn_mfma_f32_16x16x32_bf16(pa1[ks], vf, oacc1[f], 0, 0, 0);
      }
    __builtin_amdgcn_s_setprio(0);

    __syncthreads();  // drains prefetch vmcnt; all waves done with buf cur
    cur ^= 1;
  }

  // epilogue: O = q + PV/l  (oacc row = q-row g*4+j, col = d f*16+r)
  auto epilogue = [&](float lr, f32x4 (&oa)[4], int qoff) {
#pragma unroll
    for (int j = 0; j < 4; ++j) {
      float linv = 1.0f / __shfl(lr, (lane & 48) | (g * 4 + j));
      int row = q0 + qoff + g * 4 + j;
#pragma unroll
      for (int f = 0; f < 4; ++f) {
        int col = h * 64 + f * 16 + r;
        size_t idx = (rowbase + row) * DIMC + col;
        Of32[idx] = b2f(qb[idx]) + oa[f][j] * linv;
      }
    }
  };
  epilogue(lrun0, oacc0, 0);
  epilogue(lrun1, oacc1, 16);
}

extern "C" void kernel_launch(void* const* d_in, const int* in_sizes, int n_in,
                              void* d_out, int out_size, void* d_ws, size_t ws_size,
                              hipStream_t stream) {
  const float* Q  = (const float*)d_in[0];
  const float* V  = (const float*)d_in[1];
  const unsigned char* mask = (const unsigned char*)d_in[2];
  const float* Wq = (const float*)d_in[3];
  const float* bq = (const float*)d_in[4];
  const float* Wk = (const float*)d_in[5];
  const float* bk = (const float*)d_in[6];
  const float* Wv = (const float*)d_in[7];
  const float* bv = (const float*)d_in[8];
  const float* Wo = (const float*)d_in[9];
  const float* bo = (const float*)d_in[10];

  char* ws = (char*)d_ws;
  size_t off = 0;
  auto alloc = [&](size_t bytes) -> void* {
    void* p = ws + off;
    off += (bytes + 255) & ~(size_t)255;
    return p;
  };
  int* flag = (int*)alloc(4);
  unsigned short* Wqb = (unsigned short*)alloc((size_t)DIMC * DIMC * 2);
  unsigned short* Wkb = (unsigned short*)alloc((size_t)DIMC * DIMC * 2);
  unsigned short* Wvb = (unsigned short*)alloc((size_t)DIMC * DIMC * 2);
  unsigned short* Wob = (unsigned short*)alloc((size_t)DIMC * DIMC * 2);
  unsigned short* qbf = (unsigned short*)alloc((size_t)MTOK * DIMC * 2);
  unsigned short* kbf = (unsigned short*)alloc((size_t)MTOK * DIMC * 2);
  unsigned short* vtb = (unsigned short*)alloc((size_t)MTOK * DIMC * 2);
  float* Of32 = (float*)alloc((size_t)MTOK * DIMC * 4);

  hipMemsetAsync(flag, 0, 4, stream);

  cvt_all<<<4097, 256, 0, stream>>>(Wq, Wk, Wv, Wo, Wqb, Wkb, Wvb, Wob,
                                    mask, flag);

  proj_gemm<<<dim3(64, 4, 3), 256, 0, stream>>>(
      Q, V, Wqb, Wkb, Wvb, bq, bk, bv, qbf, kbf, vtb);

  attn_kernel<<<dim3(BB * 8, NTOK / 128), 256, 0, stream>>>(
      qbf, kbf, vtb, mask, flag, Of32);

  out_gemm<<<dim3(128, 4), 256, 0, stream>>>(
      Of32, Wob, bo, (float*)d_out);
}